// Round 1
// baseline (7324.715 us; speedup 1.0000x reference)
//
#include <hip/hip_runtime.h>
#include <math.h>

#define NGRAPH 64
#define EPS_BN 1e-5f

// ---------------- degree / norm ----------------
__global__ __launch_bounds__(256) void k_init_deg(float* deg, int n) {
    int i = blockIdx.x * 256 + threadIdx.x;
    if (i < n) deg[i] = 1.0f;  // self-loop
}

__global__ __launch_bounds__(256) void k_deg(const int* __restrict__ dst, float* deg, int ne) {
    int i = blockIdx.x * 256 + threadIdx.x;
    if (i < ne) atomicAdd(&deg[dst[i]], 1.0f);
}

__global__ __launch_bounds__(256) void k_dinv(const float* __restrict__ deg, float* dinv, int n) {
    int i = blockIdx.x * 256 + threadIdx.x;
    if (i < n) {
        float d = deg[i];
        dinv[i] = d > 0.f ? rsqrtf(d) : 0.f;
    }
}

// ---------------- GEMM: C[nrows x COLS] = A[nrows x 128] @ W[128 x COLS] ----------------
template<int COLS, int ROWS>
__global__ __launch_bounds__(256) void k_gemm(const float* __restrict__ A,
                                              const float* __restrict__ W,
                                              float* __restrict__ C, int nrows) {
    __shared__ float Ws[128 * COLS];
    __shared__ float As[ROWS * 128];
    const int tid = threadIdx.x;
    for (int i = tid; i < 128 * COLS; i += 256) Ws[i] = W[i];
    const int row0 = blockIdx.x * ROWS;
    for (int i = tid; i < ROWS * 128; i += 256) {
        int r = i >> 7;
        As[i] = (row0 + r < nrows) ? A[row0 * 128 + i] : 0.f;
    }
    __syncthreads();

    constexpr int CQ = COLS / 4;            // col-quads
    const int cq = tid % CQ;
    const int rq = tid / CQ;                // ROWS/4 row-quads; CQ*ROWS/4 == 256
    float acc[4][4] = {};

    #pragma unroll 4
    for (int k = 0; k < 128; ++k) {
        const float4 wv = *(const float4*)&Ws[k * COLS + 4 * cq];
        const float a0 = As[(4 * rq + 0) * 128 + k];
        const float a1 = As[(4 * rq + 1) * 128 + k];
        const float a2 = As[(4 * rq + 2) * 128 + k];
        const float a3 = As[(4 * rq + 3) * 128 + k];
        acc[0][0] = fmaf(a0, wv.x, acc[0][0]); acc[0][1] = fmaf(a0, wv.y, acc[0][1]);
        acc[0][2] = fmaf(a0, wv.z, acc[0][2]); acc[0][3] = fmaf(a0, wv.w, acc[0][3]);
        acc[1][0] = fmaf(a1, wv.x, acc[1][0]); acc[1][1] = fmaf(a1, wv.y, acc[1][1]);
        acc[1][2] = fmaf(a1, wv.z, acc[1][2]); acc[1][3] = fmaf(a1, wv.w, acc[1][3]);
        acc[2][0] = fmaf(a2, wv.x, acc[2][0]); acc[2][1] = fmaf(a2, wv.y, acc[2][1]);
        acc[2][2] = fmaf(a2, wv.z, acc[2][2]); acc[2][3] = fmaf(a2, wv.w, acc[2][3]);
        acc[3][0] = fmaf(a3, wv.x, acc[3][0]); acc[3][1] = fmaf(a3, wv.y, acc[3][1]);
        acc[3][2] = fmaf(a3, wv.z, acc[3][2]); acc[3][3] = fmaf(a3, wv.w, acc[3][3]);
    }
    #pragma unroll
    for (int r = 0; r < 4; ++r) {
        int gr = row0 + 4 * rq + r;
        if (gr < nrows) {
            float4 o = make_float4(acc[r][0], acc[r][1], acc[r][2], acc[r][3]);
            *(float4*)&C[gr * COLS + 4 * cq] = o;
        }
    }
}

// ---------------- self-loop seed: out[n] = h[n] * dinv[n]^2 ----------------
template<int COLS>
__global__ __launch_bounds__(256) void k_selfloop(const float* __restrict__ h,
                                                  const float* __restrict__ dinv,
                                                  float* __restrict__ out, int n) {
    int idx = blockIdx.x * 256 + threadIdx.x;   // over n*COLS/4 float4s
    int total = n * (COLS / 4);
    if (idx >= total) return;
    int node = idx / (COLS / 4);
    float di = dinv[node];
    float w = di * di;
    float4 v = ((const float4*)h)[idx];
    v.x *= w; v.y *= w; v.z *= w; v.w *= w;
    ((float4*)out)[idx] = v;
}

// ---------------- edge aggregation: out[dst] += h[src]*dinv[src]*dinv[dst] ----------------
template<int COLS>
__global__ __launch_bounds__(256) void k_agg(const float* __restrict__ h,
                                             const int* __restrict__ src,
                                             const int* __restrict__ dst,
                                             const float* __restrict__ dinv,
                                             float* out, int ne) {
    constexpr int TPE = COLS / 4;  // threads per edge, float4 each
    int gt = blockIdx.x * 256 + threadIdx.x;
    int e = gt / TPE;
    if (e >= ne) return;
    int lane = gt % TPE;
    int s = src[e], d = dst[e];
    float nrm = dinv[s] * dinv[d];
    float4 v = *(const float4*)&h[s * COLS + lane * 4];
    float* o = &out[d * COLS + lane * 4];
    atomicAdd(o + 0, v.x * nrm);
    atomicAdd(o + 1, v.y * nrm);
    atomicAdd(o + 2, v.z * nrm);
    atomicAdd(o + 3, v.w * nrm);
}

// ---------------- BatchNorm stats: sums[f], sums[128+f] = sum, sumsq ----------------
__global__ __launch_bounds__(256) void k_bn_stats(const float* __restrict__ x,
                                                  float* __restrict__ stats, int n) {
    const int f = threadIdx.x & 127;
    const int half = threadIdx.x >> 7;
    const int r0 = blockIdx.x * 512;
    float s = 0.f, s2 = 0.f;
    for (int j = 0; j < 256; ++j) {
        int r = r0 + half + 2 * j;
        if (r < n) {
            float v = x[r * 128 + f];
            s += v; s2 += v * v;
        }
    }
    atomicAdd(&stats[f], s);
    atomicAdd(&stats[128 + f], s2);
}

__global__ __launch_bounds__(128) void k_bn_final(const float* __restrict__ stats,
                                                  const float* __restrict__ gamma,
                                                  const float* __restrict__ beta,
                                                  float* __restrict__ ss, int n) {
    int f = threadIdx.x;
    float inv_n = 1.0f / (float)n;
    float mean = stats[f] * inv_n;
    float var = stats[128 + f] * inv_n - mean * mean;
    float scale = gamma[f] * rsqrtf(var + EPS_BN);
    ss[f] = scale;
    ss[128 + f] = beta[f] - mean * scale;
}

// ---------------- BN apply + ReLU, in place ----------------
__global__ __launch_bounds__(256) void k_bn_apply(float* __restrict__ x,
                                                  const float* __restrict__ ss, int n) {
    int idx = blockIdx.x * 256 + threadIdx.x;   // over n*32 float4s
    if (idx >= n * 32) return;
    int c4 = idx & 31;
    float4 sc = ((const float4*)ss)[c4];
    float4 sh = ((const float4*)(ss + 128))[c4];
    float4 v = ((float4*)x)[idx];
    v.x = fmaxf(fmaf(v.x, sc.x, sh.x), 0.f);
    v.y = fmaxf(fmaf(v.y, sc.y, sh.y), 0.f);
    v.z = fmaxf(fmaf(v.z, sc.z, sh.z), 0.f);
    v.w = fmaxf(fmaf(v.w, sc.w, sh.w), 0.f);
    ((float4*)x)[idx] = v;
}

// ---------------- pool: sums[g][f] += h3[n][f]; cnt[g] += 1 ----------------
__global__ __launch_bounds__(256) void k_pool(const float* __restrict__ h3,
                                              const int* __restrict__ batch,
                                              float* __restrict__ sums,
                                              float* __restrict__ cnt, int n) {
    int gt = blockIdx.x * 256 + threadIdx.x;   // 8 threads/node
    int node = gt >> 3;
    if (node >= n) return;
    int lane = gt & 7;
    int g = batch[node];
    float4 v = *(const float4*)&h3[node * 32 + lane * 4];
    float* o = &sums[g * 32 + lane * 4];
    atomicAdd(o + 0, v.x);
    atomicAdd(o + 1, v.y);
    atomicAdd(o + 2, v.z);
    atomicAdd(o + 3, v.w);
    if (lane == 0) atomicAdd(&cnt[g], 1.0f);
}

__global__ __launch_bounds__(256) void k_final(const float* __restrict__ sums,
                                               const float* __restrict__ cnt,
                                               const float* __restrict__ b3,
                                               float* __restrict__ out) {
    int i = blockIdx.x * 256 + threadIdx.x;
    if (i >= NGRAPH * 32) return;
    int g = i >> 5;
    int f = i & 31;
    float c = fmaxf(cnt[g], 1.0f);
    float v = sums[i] / c + b3[f];
    out[i] = 1.0f / (1.0f + expf(-v));
}

// ---------------- launch ----------------
extern "C" void kernel_launch(void* const* d_in, const int* in_sizes, int n_in,
                              void* d_out, int out_size, void* d_ws, size_t ws_size,
                              hipStream_t stream) {
    const float* x     = (const float*)d_in[0];
    const int*   eidx  = (const int*)d_in[1];
    const int*   batch = (const int*)d_in[2];
    const float* W1    = (const float*)d_in[3];
    const float* W2    = (const float*)d_in[5];
    const float* W3    = (const float*)d_in[7];
    const float* b3    = (const float*)d_in[8];
    const float* gamma1 = (const float*)d_in[9];
    const float* beta1  = (const float*)d_in[10];
    const float* gamma2 = (const float*)d_in[11];
    const float* beta2  = (const float*)d_in[12];

    const int N = in_sizes[0] / 128;
    const int E = in_sizes[1] / 2;
    const int* src = eidx;
    const int* dst = eidx + E;

    // workspace carve-up
    size_t off = 0;
    auto carve = [&](size_t bytes) {
        char* p = (char*)d_ws + off;
        off += (bytes + 511) & ~(size_t)511;
        return p;
    };
    const size_t NB = (size_t)N * 128 * sizeof(float);
    float* bufA  = (float*)carve(NB);              // GEMM outputs (h)
    float* bufB  = (float*)carve(NB);              // aggregation outputs
    float* deg   = (float*)carve((size_t)N * 4);
    float* dinv  = (float*)carve((size_t)N * 4);
    float* stats = (float*)carve(256 * 4);
    float* ss    = (float*)carve(256 * 4);
    float* psum  = (float*)carve(NGRAPH * 32 * 4);
    float* pcnt  = (float*)carve(NGRAPH * 4);
    (void)ws_size; (void)n_in; (void)out_size;

    const int nblkN   = (N + 255) / 256;
    const int nblkE   = (E + 255) / 256;
    const int nblkNF4 = (N * 32 + 255) / 256;       // N*128/4 elements
    const int nblkN84 = (N * 8 + 255) / 256;        // N*32/4 elements
    const int nblkAgg128 = ((size_t)E * 32 + 255) / 256;
    const int nblkAgg32  = ((size_t)E * 8 + 255) / 256;
    const int nblkPool   = (N * 8 + 255) / 256;

    // --- norms ---
    k_init_deg<<<nblkN, 256, 0, stream>>>(deg, N);
    k_deg<<<nblkE, 256, 0, stream>>>(dst, deg, E);
    k_dinv<<<nblkN, 256, 0, stream>>>(deg, dinv, N);

    // --- layer 1: h=x@W1; agg; BN+ReLU (b1 cancels under BN) ---
    k_gemm<128, 32><<<(N + 31) / 32, 256, 0, stream>>>(x, W1, bufA, N);
    k_selfloop<128><<<nblkNF4, 256, 0, stream>>>(bufA, dinv, bufB, N);
    k_agg<128><<<nblkAgg128, 256, 0, stream>>>(bufA, src, dst, dinv, bufB, E);
    hipMemsetAsync(stats, 0, 256 * 4, stream);
    k_bn_stats<<<(N + 511) / 512, 256, 0, stream>>>(bufB, stats, N);
    k_bn_final<<<1, 128, 0, stream>>>(stats, gamma1, beta1, ss, N);
    k_bn_apply<<<nblkNF4, 256, 0, stream>>>(bufB, ss, N);

    // --- layer 2 ---
    k_gemm<128, 32><<<(N + 31) / 32, 256, 0, stream>>>(bufB, W2, bufA, N);
    k_selfloop<128><<<nblkNF4, 256, 0, stream>>>(bufA, dinv, bufB, N);
    k_agg<128><<<nblkAgg128, 256, 0, stream>>>(bufA, src, dst, dinv, bufB, E);
    hipMemsetAsync(stats, 0, 256 * 4, stream);
    k_bn_stats<<<(N + 511) / 512, 256, 0, stream>>>(bufB, stats, N);
    k_bn_final<<<1, 128, 0, stream>>>(stats, gamma2, beta2, ss, N);
    k_bn_apply<<<nblkNF4, 256, 0, stream>>>(bufB, ss, N);

    // --- layer 3 (128 -> 32): h3 in bufA, agg out in bufB ---
    k_gemm<32, 128><<<(N + 127) / 128, 256, 0, stream>>>(bufB, W3, bufA, N);
    k_selfloop<32><<<nblkN84, 256, 0, stream>>>(bufA, dinv, bufB, N);
    k_agg<32><<<nblkAgg32, 256, 0, stream>>>(bufA, src, dst, dinv, bufB, E);

    // --- pool + sigmoid (b3 added post-pool; mean-pool commutes with +b3) ---
    hipMemsetAsync(psum, 0, NGRAPH * 32 * 4, stream);
    hipMemsetAsync(pcnt, 0, NGRAPH * 4, stream);
    k_pool<<<nblkPool, 256, 0, stream>>>(bufB, batch, psum, pcnt, N);
    k_final<<<(NGRAPH * 32 + 255) / 256, 256, 0, stream>>>(psum, pcnt, b3, (float*)d_out);
}

// Round 2
// 1829.031 us; speedup vs baseline: 4.0047x; 4.0047x over previous
//
#include <hip/hip_runtime.h>
#include <math.h>

#define NGRAPH 64
#define EPS_BN 1e-5f

// ---------------- degree histogram (int) ----------------
__global__ __launch_bounds__(256) void k_cnt(const int* __restrict__ dst, int* cnt, int ne) {
    int i = blockIdx.x * 256 + threadIdx.x;
    if (i < ne) atomicAdd(&cnt[dst[i]], 1);
}

__global__ __launch_bounds__(256) void k_dinv(const int* __restrict__ cnt, float* dinv, int n) {
    int i = blockIdx.x * 256 + threadIdx.x;
    if (i < n) dinv[i] = rsqrtf((float)(cnt[i] + 1));  // +1 self-loop, always > 0
}

// ---------------- single-block exclusive scan over n counts ----------------
__global__ __launch_bounds__(1024) void k_scan(const int* __restrict__ cnt,
                                               int* __restrict__ rowstart, int n) {
    __shared__ int ssum[1024];
    const int tid = threadIdx.x;
    const int per = (n + 1023) / 1024;
    const int beg = tid * per;
    const int end = min(beg + per, n);
    int s = 0;
    for (int i = beg; i < end; ++i) s += cnt[i];
    ssum[tid] = s;
    __syncthreads();
    for (int off = 1; off < 1024; off <<= 1) {
        int v = (tid >= off) ? ssum[tid - off] : 0;
        __syncthreads();
        ssum[tid] += v;
        __syncthreads();
    }
    int excl = (tid == 0) ? 0 : ssum[tid - 1];
    for (int i = beg; i < end; ++i) {
        rowstart[i] = excl;
        excl += cnt[i];
    }
}

// ---------------- scatter edges into CSR slots ----------------
__global__ __launch_bounds__(256) void k_scatter(const int* __restrict__ src,
                                                 const int* __restrict__ dst,
                                                 const int* __restrict__ rowstart,
                                                 int* __restrict__ fill,
                                                 const float* __restrict__ dinv,
                                                 int* __restrict__ esrc,
                                                 float* __restrict__ enorm, int ne) {
    int i = blockIdx.x * 256 + threadIdx.x;
    if (i >= ne) return;
    int s = src[i], d = dst[i];
    int pos = rowstart[d] + atomicAdd(&fill[d], 1);
    esrc[pos] = s;
    enorm[pos] = dinv[s] * dinv[d];
}

// ---------------- GEMM: C[nrows x COLS] = A[nrows x 128] @ W[128 x COLS] ----------------
template<int COLS, int ROWS>
__global__ __launch_bounds__(256) void k_gemm(const float* __restrict__ A,
                                              const float* __restrict__ W,
                                              float* __restrict__ C, int nrows) {
    __shared__ float Ws[128 * COLS];
    __shared__ float As[ROWS * 128];
    const int tid = threadIdx.x;
    for (int i = tid; i < 128 * COLS; i += 256) Ws[i] = W[i];
    const int row0 = blockIdx.x * ROWS;
    for (int i = tid; i < ROWS * 128; i += 256) {
        int r = i >> 7;
        As[i] = (row0 + r < nrows) ? A[row0 * 128 + i] : 0.f;
    }
    __syncthreads();

    constexpr int CQ = COLS / 4;
    const int cq = tid % CQ;
    const int rq = tid / CQ;
    float acc[4][4] = {};

    #pragma unroll 4
    for (int k = 0; k < 128; ++k) {
        const float4 wv = *(const float4*)&Ws[k * COLS + 4 * cq];
        const float a0 = As[(4 * rq + 0) * 128 + k];
        const float a1 = As[(4 * rq + 1) * 128 + k];
        const float a2 = As[(4 * rq + 2) * 128 + k];
        const float a3 = As[(4 * rq + 3) * 128 + k];
        acc[0][0] = fmaf(a0, wv.x, acc[0][0]); acc[0][1] = fmaf(a0, wv.y, acc[0][1]);
        acc[0][2] = fmaf(a0, wv.z, acc[0][2]); acc[0][3] = fmaf(a0, wv.w, acc[0][3]);
        acc[1][0] = fmaf(a1, wv.x, acc[1][0]); acc[1][1] = fmaf(a1, wv.y, acc[1][1]);
        acc[1][2] = fmaf(a1, wv.z, acc[1][2]); acc[1][3] = fmaf(a1, wv.w, acc[1][3]);
        acc[2][0] = fmaf(a2, wv.x, acc[2][0]); acc[2][1] = fmaf(a2, wv.y, acc[2][1]);
        acc[2][2] = fmaf(a2, wv.z, acc[2][2]); acc[2][3] = fmaf(a2, wv.w, acc[2][3]);
        acc[3][0] = fmaf(a3, wv.x, acc[3][0]); acc[3][1] = fmaf(a3, wv.y, acc[3][1]);
        acc[3][2] = fmaf(a3, wv.z, acc[3][2]); acc[3][3] = fmaf(a3, wv.w, acc[3][3]);
    }
    #pragma unroll
    for (int r = 0; r < 4; ++r) {
        int gr = row0 + 4 * rq + r;
        if (gr < nrows) {
            float4 o = make_float4(acc[r][0], acc[r][1], acc[r][2], acc[r][3]);
            *(float4*)&C[gr * COLS + 4 * cq] = o;
        }
    }
}

// ---------------- CSR aggregation: out[n] = h[n]*dinv[n]^2 + sum_e h[esrc]*enorm ----------------
template<int COLS>
__global__ __launch_bounds__(256) void k_agg_csr(const float* __restrict__ h,
                                                 const int* __restrict__ rowstart,
                                                 const int* __restrict__ cnt,
                                                 const int* __restrict__ esrc,
                                                 const float* __restrict__ enorm,
                                                 const float* __restrict__ dinv,
                                                 float* __restrict__ out, int n) {
    constexpr int TPN = COLS / 2;  // threads per node, float2 each
    int gt = blockIdx.x * 256 + threadIdx.x;
    int node = gt / TPN;
    if (node >= n) return;
    int lane = gt % TPN;

    float di = dinv[node];
    float2 acc = *(const float2*)&h[node * COLS + lane * 2];
    acc.x *= di * di;
    acc.y *= di * di;

    const int beg = rowstart[node];
    const int end = beg + cnt[node];
    int e = beg;
    for (; e + 2 <= end; e += 2) {
        int s0 = esrc[e], s1 = esrc[e + 1];
        float w0 = enorm[e], w1 = enorm[e + 1];
        float2 v0 = *(const float2*)&h[s0 * COLS + lane * 2];
        float2 v1 = *(const float2*)&h[s1 * COLS + lane * 2];
        acc.x = fmaf(v0.x, w0, acc.x);
        acc.y = fmaf(v0.y, w0, acc.y);
        acc.x = fmaf(v1.x, w1, acc.x);
        acc.y = fmaf(v1.y, w1, acc.y);
    }
    if (e < end) {
        int s0 = esrc[e];
        float w0 = enorm[e];
        float2 v0 = *(const float2*)&h[s0 * COLS + lane * 2];
        acc.x = fmaf(v0.x, w0, acc.x);
        acc.y = fmaf(v0.y, w0, acc.y);
    }
    *(float2*)&out[node * COLS + lane * 2] = acc;
}

// ---------------- BatchNorm stats ----------------
__global__ __launch_bounds__(256) void k_bn_stats(const float* __restrict__ x,
                                                  float* __restrict__ stats, int n) {
    const int f = threadIdx.x & 127;
    const int half = threadIdx.x >> 7;
    const int r0 = blockIdx.x * 512;
    float s = 0.f, s2 = 0.f;
    for (int j = 0; j < 256; ++j) {
        int r = r0 + half + 2 * j;
        if (r < n) {
            float v = x[r * 128 + f];
            s += v; s2 += v * v;
        }
    }
    atomicAdd(&stats[f], s);
    atomicAdd(&stats[128 + f], s2);
}

__global__ __launch_bounds__(128) void k_bn_final(const float* __restrict__ stats,
                                                  const float* __restrict__ gamma,
                                                  const float* __restrict__ beta,
                                                  float* __restrict__ ss, int n) {
    int f = threadIdx.x;
    float inv_n = 1.0f / (float)n;
    float mean = stats[f] * inv_n;
    float var = stats[128 + f] * inv_n - mean * mean;
    float scale = gamma[f] * rsqrtf(var + EPS_BN);
    ss[f] = scale;
    ss[128 + f] = beta[f] - mean * scale;
}

// ---------------- BN apply + ReLU, in place ----------------
__global__ __launch_bounds__(256) void k_bn_apply(float* __restrict__ x,
                                                  const float* __restrict__ ss, int n) {
    int idx = blockIdx.x * 256 + threadIdx.x;
    if (idx >= n * 32) return;
    int c4 = idx & 31;
    float4 sc = ((const float4*)ss)[c4];
    float4 sh = ((const float4*)(ss + 128))[c4];
    float4 v = ((float4*)x)[idx];
    v.x = fmaxf(fmaf(v.x, sc.x, sh.x), 0.f);
    v.y = fmaxf(fmaf(v.y, sc.y, sh.y), 0.f);
    v.z = fmaxf(fmaf(v.z, sc.z, sh.z), 0.f);
    v.w = fmaxf(fmaf(v.w, sc.w, sh.w), 0.f);
    ((float4*)x)[idx] = v;
}

// ---------------- pool ----------------
__global__ __launch_bounds__(256) void k_pool(const float* __restrict__ h3,
                                              const int* __restrict__ batch,
                                              float* __restrict__ sums,
                                              float* __restrict__ cnt, int n) {
    int gt = blockIdx.x * 256 + threadIdx.x;
    int node = gt >> 3;
    if (node >= n) return;
    int lane = gt & 7;
    int g = batch[node];
    float4 v = *(const float4*)&h3[node * 32 + lane * 4];
    float* o = &sums[g * 32 + lane * 4];
    atomicAdd(o + 0, v.x);
    atomicAdd(o + 1, v.y);
    atomicAdd(o + 2, v.z);
    atomicAdd(o + 3, v.w);
    if (lane == 0) atomicAdd(&cnt[g], 1.0f);
}

__global__ __launch_bounds__(256) void k_final(const float* __restrict__ sums,
                                               const float* __restrict__ cnt,
                                               const float* __restrict__ b3,
                                               float* __restrict__ out) {
    int i = blockIdx.x * 256 + threadIdx.x;
    if (i >= NGRAPH * 32) return;
    int g = i >> 5;
    int f = i & 31;
    float c = fmaxf(cnt[g], 1.0f);
    float v = sums[i] / c + b3[f];
    out[i] = 1.0f / (1.0f + expf(-v));
}

// ---------------- launch ----------------
extern "C" void kernel_launch(void* const* d_in, const int* in_sizes, int n_in,
                              void* d_out, int out_size, void* d_ws, size_t ws_size,
                              hipStream_t stream) {
    const float* x      = (const float*)d_in[0];
    const int*   eidx   = (const int*)d_in[1];
    const int*   batch  = (const int*)d_in[2];
    const float* W1     = (const float*)d_in[3];
    const float* W2     = (const float*)d_in[5];
    const float* W3     = (const float*)d_in[7];
    const float* b3     = (const float*)d_in[8];
    const float* gamma1 = (const float*)d_in[9];
    const float* beta1  = (const float*)d_in[10];
    const float* gamma2 = (const float*)d_in[11];
    const float* beta2  = (const float*)d_in[12];

    const int N = in_sizes[0] / 128;
    const int E = in_sizes[1] / 2;
    const int* src = eidx;
    const int* dst = eidx + E;

    size_t off = 0;
    auto carve = [&](size_t bytes) {
        char* p = (char*)d_ws + off;
        off += (bytes + 511) & ~(size_t)511;
        return p;
    };
    const size_t NB = (size_t)N * 128 * sizeof(float);
    float* bufA     = (float*)carve(NB);
    float* bufB     = (float*)carve(NB);
    int*   cnt      = (int*)carve((size_t)N * 4);
    int*   rowstart = (int*)carve((size_t)N * 4);
    int*   fill     = (int*)carve((size_t)N * 4);
    float* dinv     = (float*)carve((size_t)N * 4);
    int*   esrc     = (int*)carve((size_t)E * 4);
    float* enorm    = (float*)carve((size_t)E * 4);
    float* stats    = (float*)carve(256 * 4);
    float* ss       = (float*)carve(256 * 4);
    float* psum     = (float*)carve(NGRAPH * 32 * 4);
    float* pcnt     = (float*)carve(NGRAPH * 4);
    (void)ws_size; (void)n_in; (void)out_size;

    const int nblkN   = (N + 255) / 256;
    const int nblkE   = (E + 255) / 256;
    const int nblkNF4 = (N * 32 + 255) / 256;
    const int nblkAgg128 = ((size_t)N * 64 + 255) / 256;
    const int nblkAgg32  = ((size_t)N * 16 + 255) / 256;
    const int nblkPool   = (N * 8 + 255) / 256;

    // --- CSR build ---
    hipMemsetAsync(cnt, 0, (size_t)N * 4, stream);
    hipMemsetAsync(fill, 0, (size_t)N * 4, stream);
    k_cnt<<<nblkE, 256, 0, stream>>>(dst, cnt, E);
    k_dinv<<<nblkN, 256, 0, stream>>>(cnt, dinv, N);
    k_scan<<<1, 1024, 0, stream>>>(cnt, rowstart, N);
    k_scatter<<<nblkE, 256, 0, stream>>>(src, dst, rowstart, fill, dinv, esrc, enorm, E);

    // --- layer 1 (b1 cancels under BN) ---
    k_gemm<128, 32><<<(N + 31) / 32, 256, 0, stream>>>(x, W1, bufA, N);
    k_agg_csr<128><<<nblkAgg128, 256, 0, stream>>>(bufA, rowstart, cnt, esrc, enorm, dinv, bufB, N);
    hipMemsetAsync(stats, 0, 256 * 4, stream);
    k_bn_stats<<<(N + 511) / 512, 256, 0, stream>>>(bufB, stats, N);
    k_bn_final<<<1, 128, 0, stream>>>(stats, gamma1, beta1, ss, N);
    k_bn_apply<<<nblkNF4, 256, 0, stream>>>(bufB, ss, N);

    // --- layer 2 ---
    k_gemm<128, 32><<<(N + 31) / 32, 256, 0, stream>>>(bufB, W2, bufA, N);
    k_agg_csr<128><<<nblkAgg128, 256, 0, stream>>>(bufA, rowstart, cnt, esrc, enorm, dinv, bufB, N);
    hipMemsetAsync(stats, 0, 256 * 4, stream);
    k_bn_stats<<<(N + 511) / 512, 256, 0, stream>>>(bufB, stats, N);
    k_bn_final<<<1, 128, 0, stream>>>(stats, gamma2, beta2, ss, N);
    k_bn_apply<<<nblkNF4, 256, 0, stream>>>(bufB, ss, N);

    // --- layer 3 (128 -> 32) ---
    k_gemm<32, 128><<<(N + 127) / 128, 256, 0, stream>>>(bufB, W3, bufA, N);
    k_agg_csr<32><<<nblkAgg32, 256, 0, stream>>>(bufA, rowstart, cnt, esrc, enorm, dinv, bufB, N);

    // --- pool + sigmoid ---
    hipMemsetAsync(psum, 0, NGRAPH * 32 * 4, stream);
    hipMemsetAsync(pcnt, 0, NGRAPH * 4, stream);
    k_pool<<<nblkPool, 256, 0, stream>>>(bufB, batch, psum, pcnt, N);
    k_final<<<(NGRAPH * 32 + 255) / 256, 256, 0, stream>>>(psum, pcnt, b3, (float*)d_out);
}

// Round 3
// 1060.144 us; speedup vs baseline: 6.9092x; 1.7253x over previous
//
#include <hip/hip_runtime.h>
#include <math.h>

#define NGRAPH 64
#define EPS_BN 1e-5f

// ---------------- degree histogram (int) ----------------
__global__ __launch_bounds__(256) void k_cnt(const int* __restrict__ dst, int* cnt, int ne) {
    int i = blockIdx.x * 256 + threadIdx.x;
    if (i < ne) atomicAdd(&cnt[dst[i]], 1);
}

__global__ __launch_bounds__(256) void k_dinv(const int* __restrict__ cnt, float* dinv, int n) {
    int i = blockIdx.x * 256 + threadIdx.x;
    if (i < n) dinv[i] = rsqrtf((float)(cnt[i] + 1));  // +1 self-loop, always > 0
}

// ---------------- single-block exclusive scan over n counts ----------------
__global__ __launch_bounds__(1024) void k_scan(const int* __restrict__ cnt,
                                               int* __restrict__ rowstart, int n) {
    __shared__ int ssum[1024];
    const int tid = threadIdx.x;
    const int per = (n + 1023) / 1024;
    const int beg = tid * per;
    const int end = min(beg + per, n);
    int s = 0;
    for (int i = beg; i < end; ++i) s += cnt[i];
    ssum[tid] = s;
    __syncthreads();
    for (int off = 1; off < 1024; off <<= 1) {
        int v = (tid >= off) ? ssum[tid - off] : 0;
        __syncthreads();
        ssum[tid] += v;
        __syncthreads();
    }
    int excl = (tid == 0) ? 0 : ssum[tid - 1];
    for (int i = beg; i < end; ++i) {
        rowstart[i] = excl;
        excl += cnt[i];
    }
}

// ---------------- scatter edges into CSR slots ----------------
__global__ __launch_bounds__(256) void k_scatter(const int* __restrict__ src,
                                                 const int* __restrict__ dst,
                                                 const int* __restrict__ rowstart,
                                                 int* __restrict__ fill,
                                                 const float* __restrict__ dinv,
                                                 int* __restrict__ esrc,
                                                 float* __restrict__ enorm, int ne) {
    int i = blockIdx.x * 256 + threadIdx.x;
    if (i >= ne) return;
    int s = src[i], d = dst[i];
    int pos = rowstart[d] + atomicAdd(&fill[d], 1);
    esrc[pos] = s;
    enorm[pos] = dinv[s] * dinv[d];
}

// ---------------- GEMM: C[nrows x COLS] = A[nrows x 128] @ W[128 x COLS] ----------------
template<int COLS, int ROWS>
__global__ __launch_bounds__(256) void k_gemm(const float* __restrict__ A,
                                              const float* __restrict__ W,
                                              float* __restrict__ C, int nrows) {
    __shared__ float Ws[128 * COLS];
    __shared__ float As[ROWS * 128];
    const int tid = threadIdx.x;
    for (int i = tid; i < 128 * COLS; i += 256) Ws[i] = W[i];
    const int row0 = blockIdx.x * ROWS;
    for (int i = tid; i < ROWS * 128; i += 256) {
        int r = i >> 7;
        As[i] = (row0 + r < nrows) ? A[row0 * 128 + i] : 0.f;
    }
    __syncthreads();

    constexpr int CQ = COLS / 4;
    const int cq = tid % CQ;
    const int rq = tid / CQ;
    float acc[4][4] = {};

    #pragma unroll 4
    for (int k = 0; k < 128; ++k) {
        const float4 wv = *(const float4*)&Ws[k * COLS + 4 * cq];
        const float a0 = As[(4 * rq + 0) * 128 + k];
        const float a1 = As[(4 * rq + 1) * 128 + k];
        const float a2 = As[(4 * rq + 2) * 128 + k];
        const float a3 = As[(4 * rq + 3) * 128 + k];
        acc[0][0] = fmaf(a0, wv.x, acc[0][0]); acc[0][1] = fmaf(a0, wv.y, acc[0][1]);
        acc[0][2] = fmaf(a0, wv.z, acc[0][2]); acc[0][3] = fmaf(a0, wv.w, acc[0][3]);
        acc[1][0] = fmaf(a1, wv.x, acc[1][0]); acc[1][1] = fmaf(a1, wv.y, acc[1][1]);
        acc[1][2] = fmaf(a1, wv.z, acc[1][2]); acc[1][3] = fmaf(a1, wv.w, acc[1][3]);
        acc[2][0] = fmaf(a2, wv.x, acc[2][0]); acc[2][1] = fmaf(a2, wv.y, acc[2][1]);
        acc[2][2] = fmaf(a2, wv.z, acc[2][2]); acc[2][3] = fmaf(a2, wv.w, acc[2][3]);
        acc[3][0] = fmaf(a3, wv.x, acc[3][0]); acc[3][1] = fmaf(a3, wv.y, acc[3][1]);
        acc[3][2] = fmaf(a3, wv.z, acc[3][2]); acc[3][3] = fmaf(a3, wv.w, acc[3][3]);
    }
    #pragma unroll
    for (int r = 0; r < 4; ++r) {
        int gr = row0 + 4 * rq + r;
        if (gr < nrows) {
            float4 o = make_float4(acc[r][0], acc[r][1], acc[r][2], acc[r][3]);
            *(float4*)&C[gr * COLS + 4 * cq] = o;
        }
    }
}

// ---------------- CSR aggregation: out[n] = h[n]*dinv[n]^2 + sum_e h[esrc]*enorm ----------------
template<int COLS>
__global__ __launch_bounds__(256) void k_agg_csr(const float* __restrict__ h,
                                                 const int* __restrict__ rowstart,
                                                 const int* __restrict__ cnt,
                                                 const int* __restrict__ esrc,
                                                 const float* __restrict__ enorm,
                                                 const float* __restrict__ dinv,
                                                 float* __restrict__ out, int n) {
    constexpr int TPN = COLS / 2;  // threads per node, float2 each
    int gt = blockIdx.x * 256 + threadIdx.x;
    int node = gt / TPN;
    if (node >= n) return;
    int lane = gt % TPN;

    float di = dinv[node];
    float2 acc = *(const float2*)&h[node * COLS + lane * 2];
    acc.x *= di * di;
    acc.y *= di * di;

    const int beg = rowstart[node];
    const int end = beg + cnt[node];
    int e = beg;
    for (; e + 2 <= end; e += 2) {
        int s0 = esrc[e], s1 = esrc[e + 1];
        float w0 = enorm[e], w1 = enorm[e + 1];
        float2 v0 = *(const float2*)&h[s0 * COLS + lane * 2];
        float2 v1 = *(const float2*)&h[s1 * COLS + lane * 2];
        acc.x = fmaf(v0.x, w0, acc.x);
        acc.y = fmaf(v0.y, w0, acc.y);
        acc.x = fmaf(v1.x, w1, acc.x);
        acc.y = fmaf(v1.y, w1, acc.y);
    }
    if (e < end) {
        int s0 = esrc[e];
        float w0 = enorm[e];
        float2 v0 = *(const float2*)&h[s0 * COLS + lane * 2];
        acc.x = fmaf(v0.x, w0, acc.x);
        acc.y = fmaf(v0.y, w0, acc.y);
    }
    *(float2*)&out[node * COLS + lane * 2] = acc;
}

// ---------------- BatchNorm stats ----------------
__global__ __launch_bounds__(256) void k_bn_stats(const float* __restrict__ x,
                                                  float* __restrict__ stats, int n) {
    const int f = threadIdx.x & 127;
    const int half = threadIdx.x >> 7;
    const int r0 = blockIdx.x * 512;
    float s = 0.f, s2 = 0.f;
    for (int j = 0; j < 256; ++j) {
        int r = r0 + half + 2 * j;
        if (r < n) {
            float v = x[r * 128 + f];
            s += v; s2 += v * v;
        }
    }
    atomicAdd(&stats[f], s);
    atomicAdd(&stats[128 + f], s2);
}

__global__ __launch_bounds__(128) void k_bn_final(const float* __restrict__ stats,
                                                  const float* __restrict__ gamma,
                                                  const float* __restrict__ beta,
                                                  float* __restrict__ ss, int n) {
    int f = threadIdx.x;
    float inv_n = 1.0f / (float)n;
    float mean = stats[f] * inv_n;
    float var = stats[128 + f] * inv_n - mean * mean;
    float scale = gamma[f] * rsqrtf(var + EPS_BN);
    ss[f] = scale;
    ss[128 + f] = beta[f] - mean * scale;
}

// ---------------- BN apply + ReLU, in place ----------------
__global__ __launch_bounds__(256) void k_bn_apply(float* __restrict__ x,
                                                  const float* __restrict__ ss, int n) {
    int idx = blockIdx.x * 256 + threadIdx.x;
    if (idx >= n * 32) return;
    int c4 = idx & 31;
    float4 sc = ((const float4*)ss)[c4];
    float4 sh = ((const float4*)(ss + 128))[c4];
    float4 v = ((float4*)x)[idx];
    v.x = fmaxf(fmaf(v.x, sc.x, sh.x), 0.f);
    v.y = fmaxf(fmaf(v.y, sc.y, sh.y), 0.f);
    v.z = fmaxf(fmaf(v.z, sc.z, sh.z), 0.f);
    v.w = fmaxf(fmaf(v.w, sc.w, sh.w), 0.f);
    ((float4*)x)[idx] = v;
}

// ---------------- pool: sorted-batch run-length private accumulation ----------------
// Block = 256 threads: f = tid&31 (feature), sub = tid>>5 (8 slices of 128 nodes).
// Each thread privately accumulates its feature over a contiguous 128-node slice,
// flushing to global atomics only when the (sorted) graph id changes.
#define POOL_SLICE 128
__global__ __launch_bounds__(256) void k_pool2(const float* __restrict__ h3,
                                               const int* __restrict__ batch,
                                               float* __restrict__ sums,
                                               float* __restrict__ cnt, int n) {
    const int f = threadIdx.x & 31;
    const int sub = threadIdx.x >> 5;
    int node0 = blockIdx.x * (8 * POOL_SLICE) + sub * POOL_SLICE;
    if (node0 >= n) return;
    int node1 = min(node0 + POOL_SLICE, n);

    int cur_g = batch[node0];
    float acc = 0.f;
    float c = 0.f;
    for (int i = node0; i < node1; ++i) {
        int g = batch[i];
        if (g != cur_g) {
            atomicAdd(&sums[cur_g * 32 + f], acc);
            if (f == 0) atomicAdd(&cnt[cur_g], c);
            acc = 0.f; c = 0.f; cur_g = g;
        }
        acc += h3[i * 32 + f];
        c += 1.f;
    }
    atomicAdd(&sums[cur_g * 32 + f], acc);
    if (f == 0) atomicAdd(&cnt[cur_g], c);
}

__global__ __launch_bounds__(256) void k_final(const float* __restrict__ sums,
                                               const float* __restrict__ cnt,
                                               const float* __restrict__ b3,
                                               float* __restrict__ out) {
    int i = blockIdx.x * 256 + threadIdx.x;
    if (i >= NGRAPH * 32) return;
    int g = i >> 5;
    int f = i & 31;
    float c = fmaxf(cnt[g], 1.0f);
    float v = sums[i] / c + b3[f];
    out[i] = 1.0f / (1.0f + expf(-v));
}

// ---------------- launch ----------------
extern "C" void kernel_launch(void* const* d_in, const int* in_sizes, int n_in,
                              void* d_out, int out_size, void* d_ws, size_t ws_size,
                              hipStream_t stream) {
    const float* x      = (const float*)d_in[0];
    const int*   eidx   = (const int*)d_in[1];
    const int*   batch  = (const int*)d_in[2];
    const float* W1     = (const float*)d_in[3];
    const float* W2     = (const float*)d_in[5];
    const float* W3     = (const float*)d_in[7];
    const float* b3     = (const float*)d_in[8];
    const float* gamma1 = (const float*)d_in[9];
    const float* beta1  = (const float*)d_in[10];
    const float* gamma2 = (const float*)d_in[11];
    const float* beta2  = (const float*)d_in[12];

    const int N = in_sizes[0] / 128;
    const int E = in_sizes[1] / 2;
    const int* src = eidx;
    const int* dst = eidx + E;

    size_t off = 0;
    auto carve = [&](size_t bytes) {
        char* p = (char*)d_ws + off;
        off += (bytes + 511) & ~(size_t)511;
        return p;
    };
    const size_t NB = (size_t)N * 128 * sizeof(float);
    float* bufA     = (float*)carve(NB);
    float* bufB     = (float*)carve(NB);
    int*   cnt      = (int*)carve((size_t)N * 4);
    int*   rowstart = (int*)carve((size_t)N * 4);
    int*   fill     = (int*)carve((size_t)N * 4);
    float* dinv     = (float*)carve((size_t)N * 4);
    int*   esrc     = (int*)carve((size_t)E * 4);
    float* enorm    = (float*)carve((size_t)E * 4);
    float* stats    = (float*)carve(256 * 4);
    float* ss       = (float*)carve(256 * 4);
    float* psum     = (float*)carve(NGRAPH * 32 * 4);
    float* pcnt     = (float*)carve(NGRAPH * 4);
    (void)ws_size; (void)n_in; (void)out_size;

    const int nblkN   = (N + 255) / 256;
    const int nblkE   = (E + 255) / 256;
    const int nblkNF4 = (N * 32 + 255) / 256;
    const int nblkAgg128 = ((size_t)N * 64 + 255) / 256;
    const int nblkAgg32  = ((size_t)N * 16 + 255) / 256;
    const int nblkPool   = (N + 8 * POOL_SLICE - 1) / (8 * POOL_SLICE);

    // --- CSR build ---
    hipMemsetAsync(cnt, 0, (size_t)N * 4, stream);
    hipMemsetAsync(fill, 0, (size_t)N * 4, stream);
    k_cnt<<<nblkE, 256, 0, stream>>>(dst, cnt, E);
    k_dinv<<<nblkN, 256, 0, stream>>>(cnt, dinv, N);
    k_scan<<<1, 1024, 0, stream>>>(cnt, rowstart, N);
    k_scatter<<<nblkE, 256, 0, stream>>>(src, dst, rowstart, fill, dinv, esrc, enorm, E);

    // --- layer 1 (b1 cancels under BN) ---
    k_gemm<128, 32><<<(N + 31) / 32, 256, 0, stream>>>(x, W1, bufA, N);
    k_agg_csr<128><<<nblkAgg128, 256, 0, stream>>>(bufA, rowstart, cnt, esrc, enorm, dinv, bufB, N);
    hipMemsetAsync(stats, 0, 256 * 4, stream);
    k_bn_stats<<<(N + 511) / 512, 256, 0, stream>>>(bufB, stats, N);
    k_bn_final<<<1, 128, 0, stream>>>(stats, gamma1, beta1, ss, N);
    k_bn_apply<<<nblkNF4, 256, 0, stream>>>(bufB, ss, N);

    // --- layer 2 ---
    k_gemm<128, 32><<<(N + 31) / 32, 256, 0, stream>>>(bufB, W2, bufA, N);
    k_agg_csr<128><<<nblkAgg128, 256, 0, stream>>>(bufA, rowstart, cnt, esrc, enorm, dinv, bufB, N);
    hipMemsetAsync(stats, 0, 256 * 4, stream);
    k_bn_stats<<<(N + 511) / 512, 256, 0, stream>>>(bufB, stats, N);
    k_bn_final<<<1, 128, 0, stream>>>(stats, gamma2, beta2, ss, N);
    k_bn_apply<<<nblkNF4, 256, 0, stream>>>(bufB, ss, N);

    // --- layer 3 (128 -> 32) ---
    k_gemm<32, 128><<<(N + 127) / 128, 256, 0, stream>>>(bufB, W3, bufA, N);
    k_agg_csr<32><<<nblkAgg32, 256, 0, stream>>>(bufA, rowstart, cnt, esrc, enorm, dinv, bufB, N);

    // --- pool + sigmoid ---
    hipMemsetAsync(psum, 0, NGRAPH * 32 * 4, stream);
    hipMemsetAsync(pcnt, 0, NGRAPH * 4, stream);
    k_pool2<<<nblkPool, 256, 0, stream>>>(bufB, batch, psum, pcnt, N);
    k_final<<<(NGRAPH * 32 + 255) / 256, 256, 0, stream>>>(psum, pcnt, b3, (float*)d_out);
}

// Round 4
// 881.120 us; speedup vs baseline: 8.3130x; 1.2032x over previous
//
#include <hip/hip_runtime.h>
#include <math.h>

#define NGRAPH 64
#define EPS_BN 1e-5f

// ---------------- degree histogram (int) ----------------
__global__ __launch_bounds__(256) void k_cnt(const int* __restrict__ dst, int* cnt, int ne) {
    int i = blockIdx.x * 256 + threadIdx.x;
    if (i < ne) atomicAdd(&cnt[dst[i]], 1);
}

// ---------------- hierarchical exclusive scan ----------------
// scan1: per-block (1024) LDS scan; writes local-exclusive prefix, block total, and dinv.
__global__ __launch_bounds__(1024) void k_scan1(const int* __restrict__ cnt,
                                                int* __restrict__ rowstart,
                                                int* __restrict__ blocksum,
                                                float* __restrict__ dinv, int n) {
    __shared__ int sh[1024];
    const int tid = threadIdx.x;
    const int i = blockIdx.x * 1024 + tid;
    int v = (i < n) ? cnt[i] : 0;
    if (i < n) dinv[i] = rsqrtf((float)(v + 1));  // +1 self-loop, always > 0
    sh[tid] = v;
    __syncthreads();
    for (int off = 1; off < 1024; off <<= 1) {
        int t = (tid >= off) ? sh[tid - off] : 0;
        __syncthreads();
        sh[tid] += t;
        __syncthreads();
    }
    if (i < n) rowstart[i] = sh[tid] - v;  // exclusive in-block
    if (tid == 1023) blocksum[blockIdx.x] = sh[1023];
}

// scan2: single block scans the block sums (exclusive) in place.
__global__ __launch_bounds__(1024) void k_scan2(int* __restrict__ blocksum, int nb) {
    __shared__ int sh[1024];
    const int tid = threadIdx.x;
    int v = (tid < nb) ? blocksum[tid] : 0;
    sh[tid] = v;
    __syncthreads();
    for (int off = 1; off < 1024; off <<= 1) {
        int t = (tid >= off) ? sh[tid - off] : 0;
        __syncthreads();
        sh[tid] += t;
        __syncthreads();
    }
    if (tid < nb) blocksum[tid] = sh[tid] - v;  // exclusive
}

// scan3: add block offsets.
__global__ __launch_bounds__(256) void k_scan3(int* __restrict__ rowstart,
                                               const int* __restrict__ blocksum, int n) {
    int i = blockIdx.x * 256 + threadIdx.x;
    if (i < n) rowstart[i] += blocksum[i >> 10];
}

// ---------------- scatter edges into CSR slots ----------------
__global__ __launch_bounds__(256) void k_scatter(const int* __restrict__ src,
                                                 const int* __restrict__ dst,
                                                 const int* __restrict__ rowstart,
                                                 int* __restrict__ fill,
                                                 const float* __restrict__ dinv,
                                                 int* __restrict__ esrc,
                                                 float* __restrict__ enorm, int ne) {
    int i = blockIdx.x * 256 + threadIdx.x;
    if (i >= ne) return;
    int s = src[i], d = dst[i];
    int pos = rowstart[d] + atomicAdd(&fill[d], 1);
    esrc[pos] = s;
    enorm[pos] = dinv[s] * dinv[d];
}

// ---------------- GEMM: C = act(A) @ W, optional fused BN+ReLU on A ----------------
// BN: a' = max(a*ss[f] + ss[128+f], 0) applied during LDS staging (f = col of A).
template<int COLS, int ROWS, bool BN>
__global__ __launch_bounds__(256) void k_gemm(const float* __restrict__ A,
                                              const float* __restrict__ W,
                                              const float* __restrict__ ss,
                                              float* __restrict__ C, int nrows) {
    __shared__ float Ws[128 * COLS];
    __shared__ float As[ROWS * 128];
    const int tid = threadIdx.x;
    for (int i = tid; i < 128 * COLS; i += 256) Ws[i] = W[i];
    const int row0 = blockIdx.x * ROWS;
    for (int i = tid; i < ROWS * 128; i += 256) {
        int r = i >> 7;
        float a = (row0 + r < nrows) ? A[row0 * 128 + i] : 0.f;
        if (BN) {
            int f = i & 127;
            a = fmaxf(fmaf(a, ss[f], ss[128 + f]), 0.f);
        }
        As[i] = a;
    }
    __syncthreads();

    constexpr int CQ = COLS / 4;
    const int cq = tid % CQ;
    const int rq = tid / CQ;
    float acc[4][4] = {};

    #pragma unroll 4
    for (int k = 0; k < 128; ++k) {
        const float4 wv = *(const float4*)&Ws[k * COLS + 4 * cq];
        const float a0 = As[(4 * rq + 0) * 128 + k];
        const float a1 = As[(4 * rq + 1) * 128 + k];
        const float a2 = As[(4 * rq + 2) * 128 + k];
        const float a3 = As[(4 * rq + 3) * 128 + k];
        acc[0][0] = fmaf(a0, wv.x, acc[0][0]); acc[0][1] = fmaf(a0, wv.y, acc[0][1]);
        acc[0][2] = fmaf(a0, wv.z, acc[0][2]); acc[0][3] = fmaf(a0, wv.w, acc[0][3]);
        acc[1][0] = fmaf(a1, wv.x, acc[1][0]); acc[1][1] = fmaf(a1, wv.y, acc[1][1]);
        acc[1][2] = fmaf(a1, wv.z, acc[1][2]); acc[1][3] = fmaf(a1, wv.w, acc[1][3]);
        acc[2][0] = fmaf(a2, wv.x, acc[2][0]); acc[2][1] = fmaf(a2, wv.y, acc[2][1]);
        acc[2][2] = fmaf(a2, wv.z, acc[2][2]); acc[2][3] = fmaf(a2, wv.w, acc[2][3]);
        acc[3][0] = fmaf(a3, wv.x, acc[3][0]); acc[3][1] = fmaf(a3, wv.y, acc[3][1]);
        acc[3][2] = fmaf(a3, wv.z, acc[3][2]); acc[3][3] = fmaf(a3, wv.w, acc[3][3]);
    }
    #pragma unroll
    for (int r = 0; r < 4; ++r) {
        int gr = row0 + 4 * rq + r;
        if (gr < nrows) {
            float4 o = make_float4(acc[r][0], acc[r][1], acc[r][2], acc[r][3]);
            *(float4*)&C[gr * COLS + 4 * cq] = o;
        }
    }
}

// ---------------- CSR aggregation: out[n] = h[n]*dinv[n]^2 + sum_e h[esrc]*enorm ----------------
template<int COLS>
__global__ __launch_bounds__(256) void k_agg_csr(const float* __restrict__ h,
                                                 const int* __restrict__ rowstart,
                                                 const int* __restrict__ cnt,
                                                 const int* __restrict__ esrc,
                                                 const float* __restrict__ enorm,
                                                 const float* __restrict__ dinv,
                                                 float* __restrict__ out, int n) {
    constexpr int TPN = COLS / 2;  // threads per node, float2 each
    int gt = blockIdx.x * 256 + threadIdx.x;
    int node = gt / TPN;
    if (node >= n) return;
    int lane = gt % TPN;

    float di = dinv[node];
    float2 acc = *(const float2*)&h[node * COLS + lane * 2];
    acc.x *= di * di;
    acc.y *= di * di;

    const int beg = rowstart[node];
    const int end = beg + cnt[node];
    int e = beg;
    for (; e + 2 <= end; e += 2) {
        int s0 = esrc[e], s1 = esrc[e + 1];
        float w0 = enorm[e], w1 = enorm[e + 1];
        float2 v0 = *(const float2*)&h[s0 * COLS + lane * 2];
        float2 v1 = *(const float2*)&h[s1 * COLS + lane * 2];
        acc.x = fmaf(v0.x, w0, acc.x);
        acc.y = fmaf(v0.y, w0, acc.y);
        acc.x = fmaf(v1.x, w1, acc.x);
        acc.y = fmaf(v1.y, w1, acc.y);
    }
    if (e < end) {
        int s0 = esrc[e];
        float w0 = enorm[e];
        float2 v0 = *(const float2*)&h[s0 * COLS + lane * 2];
        acc.x = fmaf(v0.x, w0, acc.x);
        acc.y = fmaf(v0.y, w0, acc.y);
    }
    *(float2*)&out[node * COLS + lane * 2] = acc;
}

// ---------------- BatchNorm stats ----------------
__global__ __launch_bounds__(256) void k_bn_stats(const float* __restrict__ x,
                                                  float* __restrict__ stats, int n) {
    const int f = threadIdx.x & 127;
    const int half = threadIdx.x >> 7;
    const int r0 = blockIdx.x * 512;
    float s = 0.f, s2 = 0.f;
    for (int j = 0; j < 256; ++j) {
        int r = r0 + half + 2 * j;
        if (r < n) {
            float v = x[r * 128 + f];
            s += v; s2 += v * v;
        }
    }
    atomicAdd(&stats[f], s);
    atomicAdd(&stats[128 + f], s2);
}

__global__ __launch_bounds__(128) void k_bn_final(const float* __restrict__ stats,
                                                  const float* __restrict__ gamma,
                                                  const float* __restrict__ beta,
                                                  float* __restrict__ ss, int n) {
    int f = threadIdx.x;
    float inv_n = 1.0f / (float)n;
    float mean = stats[f] * inv_n;
    float var = stats[128 + f] * inv_n - mean * mean;
    float scale = gamma[f] * rsqrtf(var + EPS_BN);
    ss[f] = scale;
    ss[128 + f] = beta[f] - mean * scale;
}

// ---------------- pool: sorted-batch run-length private accumulation ----------------
#define POOL_SLICE 128
__global__ __launch_bounds__(256) void k_pool2(const float* __restrict__ h3,
                                               const int* __restrict__ batch,
                                               float* __restrict__ sums,
                                               float* __restrict__ cnt, int n) {
    const int f = threadIdx.x & 31;
    const int sub = threadIdx.x >> 5;
    int node0 = blockIdx.x * (8 * POOL_SLICE) + sub * POOL_SLICE;
    if (node0 >= n) return;
    int node1 = min(node0 + POOL_SLICE, n);

    int cur_g = batch[node0];
    float acc = 0.f;
    float c = 0.f;
    for (int i = node0; i < node1; ++i) {
        int g = batch[i];
        if (g != cur_g) {
            atomicAdd(&sums[cur_g * 32 + f], acc);
            if (f == 0) atomicAdd(&cnt[cur_g], c);
            acc = 0.f; c = 0.f; cur_g = g;
        }
        acc += h3[i * 32 + f];
        c += 1.f;
    }
    atomicAdd(&sums[cur_g * 32 + f], acc);
    if (f == 0) atomicAdd(&cnt[cur_g], c);
}

__global__ __launch_bounds__(256) void k_final(const float* __restrict__ sums,
                                               const float* __restrict__ cnt,
                                               const float* __restrict__ b3,
                                               float* __restrict__ out) {
    int i = blockIdx.x * 256 + threadIdx.x;
    if (i >= NGRAPH * 32) return;
    int g = i >> 5;
    int f = i & 31;
    float c = fmaxf(cnt[g], 1.0f);
    float v = sums[i] / c + b3[f];
    out[i] = 1.0f / (1.0f + expf(-v));
}

// ---------------- launch ----------------
extern "C" void kernel_launch(void* const* d_in, const int* in_sizes, int n_in,
                              void* d_out, int out_size, void* d_ws, size_t ws_size,
                              hipStream_t stream) {
    const float* x      = (const float*)d_in[0];
    const int*   eidx   = (const int*)d_in[1];
    const int*   batch  = (const int*)d_in[2];
    const float* W1     = (const float*)d_in[3];
    const float* W2     = (const float*)d_in[5];
    const float* W3     = (const float*)d_in[7];
    const float* b3     = (const float*)d_in[8];
    const float* gamma1 = (const float*)d_in[9];
    const float* beta1  = (const float*)d_in[10];
    const float* gamma2 = (const float*)d_in[11];
    const float* beta2  = (const float*)d_in[12];

    const int N = in_sizes[0] / 128;
    const int E = in_sizes[1] / 2;
    const int* src = eidx;
    const int* dst = eidx + E;

    size_t off = 0;
    auto carve = [&](size_t bytes) {
        char* p = (char*)d_ws + off;
        off += (bytes + 511) & ~(size_t)511;
        return p;
    };
    const size_t NB = (size_t)N * 128 * sizeof(float);
    float* bufA     = (float*)carve(NB);
    float* bufB     = (float*)carve(NB);
    int*   cnt      = (int*)carve((size_t)N * 4);
    int*   rowstart = (int*)carve((size_t)N * 4);
    int*   fill     = (int*)carve((size_t)N * 4);
    float* dinv     = (float*)carve((size_t)N * 4);
    int*   esrc     = (int*)carve((size_t)E * 4);
    float* enorm    = (float*)carve((size_t)E * 4);
    float* stats    = (float*)carve(256 * 4);
    float* ss1      = (float*)carve(256 * 4);
    float* ss2      = (float*)carve(256 * 4);
    int*   blocksum = (int*)carve(1024 * 4);
    float* psum     = (float*)carve(NGRAPH * 32 * 4);
    float* pcnt     = (float*)carve(NGRAPH * 4);
    (void)ws_size; (void)n_in; (void)out_size;

    const int nblkN   = (N + 255) / 256;
    const int nblkE   = (E + 255) / 256;
    const int nbScan  = (N + 1023) / 1024;
    const int nblkAgg128 = ((size_t)N * 64 + 255) / 256;
    const int nblkAgg32  = ((size_t)N * 16 + 255) / 256;
    const int nblkPool   = (N + 8 * POOL_SLICE - 1) / (8 * POOL_SLICE);

    // --- CSR build ---
    hipMemsetAsync(cnt, 0, (size_t)N * 4, stream);
    hipMemsetAsync(fill, 0, (size_t)N * 4, stream);
    k_cnt<<<nblkE, 256, 0, stream>>>(dst, cnt, E);
    k_scan1<<<nbScan, 1024, 0, stream>>>(cnt, rowstart, blocksum, dinv, N);
    k_scan2<<<1, 1024, 0, stream>>>(blocksum, nbScan);
    k_scan3<<<nblkN, 256, 0, stream>>>(rowstart, blocksum, N);
    k_scatter<<<nblkE, 256, 0, stream>>>(src, dst, rowstart, fill, dinv, esrc, enorm, E);

    // --- layer 1 (b1 cancels under BN) ---
    k_gemm<128, 32, false><<<(N + 31) / 32, 256, 0, stream>>>(x, W1, nullptr, bufA, N);
    k_agg_csr<128><<<nblkAgg128, 256, 0, stream>>>(bufA, rowstart, cnt, esrc, enorm, dinv, bufB, N);
    hipMemsetAsync(stats, 0, 256 * 4, stream);
    k_bn_stats<<<(N + 511) / 512, 256, 0, stream>>>(bufB, stats, N);
    k_bn_final<<<1, 128, 0, stream>>>(stats, gamma1, beta1, ss1, N);

    // --- layer 2 (BN1+ReLU fused into A-staging) ---
    k_gemm<128, 32, true><<<(N + 31) / 32, 256, 0, stream>>>(bufB, W2, ss1, bufA, N);
    k_agg_csr<128><<<nblkAgg128, 256, 0, stream>>>(bufA, rowstart, cnt, esrc, enorm, dinv, bufB, N);
    hipMemsetAsync(stats, 0, 256 * 4, stream);
    k_bn_stats<<<(N + 511) / 512, 256, 0, stream>>>(bufB, stats, N);
    k_bn_final<<<1, 128, 0, stream>>>(stats, gamma2, beta2, ss2, N);

    // --- layer 3 (128 -> 32, BN2+ReLU fused) ---
    k_gemm<32, 128, true><<<(N + 127) / 128, 256, 0, stream>>>(bufB, W3, ss2, bufA, N);
    k_agg_csr<32><<<nblkAgg32, 256, 0, stream>>>(bufA, rowstart, cnt, esrc, enorm, dinv, bufB, N);

    // --- pool + sigmoid (b3 added post-pool) ---
    hipMemsetAsync(psum, 0, NGRAPH * 32 * 4, stream);
    hipMemsetAsync(pcnt, 0, NGRAPH * 4, stream);
    k_pool2<<<nblkPool, 256, 0, stream>>>(bufB, batch, psum, pcnt, N);
    k_final<<<(NGRAPH * 32 + 255) / 256, 256, 0, stream>>>(psum, pcnt, b3, (float*)d_out);
}

// Round 5
// 763.073 us; speedup vs baseline: 9.5990x; 1.1547x over previous
//
#include <hip/hip_runtime.h>
#include <math.h>

#define NGRAPH 64
#define EPS_BN 1e-5f

typedef unsigned int uint32;
typedef unsigned short ushort16;

__device__ __forceinline__ float bf2f(uint32 u16) {
    return __uint_as_float(u16 << 16);
}
__device__ __forceinline__ ushort16 f2bf(float f) {
    uint32 u = __float_as_uint(f);
    return (ushort16)((u + 0x7fffu + ((u >> 16) & 1u)) >> 16);  // RNE
}

// ---------------- degree histogram (int) ----------------
__global__ __launch_bounds__(256) void k_cnt(const int* __restrict__ dst, int* cnt, int ne) {
    int i = blockIdx.x * 256 + threadIdx.x;
    if (i < ne) atomicAdd(&cnt[dst[i]], 1);
}

// ---------------- hierarchical exclusive scan ----------------
__global__ __launch_bounds__(1024) void k_scan1(const int* __restrict__ cnt,
                                                int* __restrict__ rowstart,
                                                int* __restrict__ blocksum,
                                                float* __restrict__ dinv, int n) {
    __shared__ int sh[1024];
    const int tid = threadIdx.x;
    const int i = blockIdx.x * 1024 + tid;
    int v = (i < n) ? cnt[i] : 0;
    if (i < n) dinv[i] = rsqrtf((float)(v + 1));  // +1 self-loop, always > 0
    sh[tid] = v;
    __syncthreads();
    for (int off = 1; off < 1024; off <<= 1) {
        int t = (tid >= off) ? sh[tid - off] : 0;
        __syncthreads();
        sh[tid] += t;
        __syncthreads();
    }
    if (i < n) rowstart[i] = sh[tid] - v;  // exclusive in-block
    if (tid == 1023) blocksum[blockIdx.x] = sh[1023];
}

__global__ __launch_bounds__(1024) void k_scan2(int* __restrict__ blocksum, int nb) {
    __shared__ int sh[1024];
    const int tid = threadIdx.x;
    int v = (tid < nb) ? blocksum[tid] : 0;
    sh[tid] = v;
    __syncthreads();
    for (int off = 1; off < 1024; off <<= 1) {
        int t = (tid >= off) ? sh[tid - off] : 0;
        __syncthreads();
        sh[tid] += t;
        __syncthreads();
    }
    if (tid < nb) blocksum[tid] = sh[tid] - v;  // exclusive
}

__global__ __launch_bounds__(256) void k_scan3(int* __restrict__ rowstart,
                                               const int* __restrict__ blocksum, int n) {
    int i = blockIdx.x * 256 + threadIdx.x;
    if (i < n) rowstart[i] += blocksum[i >> 10];
}

// ---------------- scatter edges into CSR slots ----------------
__global__ __launch_bounds__(256) void k_scatter(const int* __restrict__ src,
                                                 const int* __restrict__ dst,
                                                 const int* __restrict__ rowstart,
                                                 int* __restrict__ fill,
                                                 const float* __restrict__ dinv,
                                                 int* __restrict__ esrc,
                                                 float* __restrict__ enorm, int ne) {
    int i = blockIdx.x * 256 + threadIdx.x;
    if (i >= ne) return;
    int s = src[i], d = dst[i];
    int pos = rowstart[d] + atomicAdd(&fill[d], 1);
    esrc[pos] = s;
    enorm[pos] = dinv[s] * dinv[d];
}

// ---------------- GEMM: C(bf16) = act(A) @ W, optional fused BN+ReLU on A ----------------
template<int COLS, int ROWS, bool BN>
__global__ __launch_bounds__(256) void k_gemm(const float* __restrict__ A,
                                              const float* __restrict__ W,
                                              const float* __restrict__ ss,
                                              ushort16* __restrict__ C, int nrows) {
    __shared__ float Ws[128 * COLS];
    __shared__ float As[ROWS * 128];
    const int tid = threadIdx.x;
    for (int i = tid; i < 128 * COLS; i += 256) Ws[i] = W[i];
    const int row0 = blockIdx.x * ROWS;
    for (int i = tid; i < ROWS * 128; i += 256) {
        int r = i >> 7;
        float a = (row0 + r < nrows) ? A[row0 * 128 + i] : 0.f;
        if (BN) {
            int f = i & 127;
            a = fmaxf(fmaf(a, ss[f], ss[128 + f]), 0.f);
        }
        As[i] = a;
    }
    __syncthreads();

    constexpr int CQ = COLS / 4;
    const int cq = tid % CQ;
    const int rq = tid / CQ;
    float acc[4][4] = {};

    #pragma unroll 4
    for (int k = 0; k < 128; ++k) {
        const float4 wv = *(const float4*)&Ws[k * COLS + 4 * cq];
        const float a0 = As[(4 * rq + 0) * 128 + k];
        const float a1 = As[(4 * rq + 1) * 128 + k];
        const float a2 = As[(4 * rq + 2) * 128 + k];
        const float a3 = As[(4 * rq + 3) * 128 + k];
        acc[0][0] = fmaf(a0, wv.x, acc[0][0]); acc[0][1] = fmaf(a0, wv.y, acc[0][1]);
        acc[0][2] = fmaf(a0, wv.z, acc[0][2]); acc[0][3] = fmaf(a0, wv.w, acc[0][3]);
        acc[1][0] = fmaf(a1, wv.x, acc[1][0]); acc[1][1] = fmaf(a1, wv.y, acc[1][1]);
        acc[1][2] = fmaf(a1, wv.z, acc[1][2]); acc[1][3] = fmaf(a1, wv.w, acc[1][3]);
        acc[2][0] = fmaf(a2, wv.x, acc[2][0]); acc[2][1] = fmaf(a2, wv.y, acc[2][1]);
        acc[2][2] = fmaf(a2, wv.z, acc[2][2]); acc[2][3] = fmaf(a2, wv.w, acc[2][3]);
        acc[3][0] = fmaf(a3, wv.x, acc[3][0]); acc[3][1] = fmaf(a3, wv.y, acc[3][1]);
        acc[3][2] = fmaf(a3, wv.z, acc[3][2]); acc[3][3] = fmaf(a3, wv.w, acc[3][3]);
    }
    #pragma unroll
    for (int r = 0; r < 4; ++r) {
        int gr = row0 + 4 * rq + r;
        if (gr < nrows) {
            ushort4 o;
            o.x = f2bf(acc[r][0]); o.y = f2bf(acc[r][1]);
            o.z = f2bf(acc[r][2]); o.w = f2bf(acc[r][3]);
            *(ushort4*)&C[gr * COLS + 4 * cq] = o;
        }
    }
}

// ---------------- CSR aggregation (bf16 gather, fp32 accum) ----------------
// out[n] = h[n]*dinv[n]^2 + sum_e h[esrc]*enorm ; h stored bf16, out fp32.
template<int COLS>
__global__ __launch_bounds__(256) void k_agg_csr(const ushort16* __restrict__ h,
                                                 const int* __restrict__ rowstart,
                                                 const int* __restrict__ cnt,
                                                 const int* __restrict__ esrc,
                                                 const float* __restrict__ enorm,
                                                 const float* __restrict__ dinv,
                                                 float* __restrict__ out, int n) {
    constexpr int TPN = COLS / 2;  // threads per node, 2 bf16 (one uint) each
    const uint32* __restrict__ hu = (const uint32*)h;
    int gt = blockIdx.x * 256 + threadIdx.x;
    int node = gt / TPN;
    if (node >= n) return;
    int lane = gt % TPN;

    float di = dinv[node];
    uint32 p = hu[node * TPN + lane];
    float ax = bf2f(p & 0xffffu) * di * di;
    float ay = bf2f(p >> 16) * di * di;

    const int beg = rowstart[node];
    const int end = beg + cnt[node];
    int e = beg;
    for (; e + 4 <= end; e += 4) {
        int s0 = esrc[e], s1 = esrc[e + 1], s2 = esrc[e + 2], s3 = esrc[e + 3];
        float w0 = enorm[e], w1 = enorm[e + 1], w2 = enorm[e + 2], w3 = enorm[e + 3];
        uint32 p0 = hu[s0 * TPN + lane];
        uint32 p1 = hu[s1 * TPN + lane];
        uint32 p2 = hu[s2 * TPN + lane];
        uint32 p3 = hu[s3 * TPN + lane];
        ax = fmaf(bf2f(p0 & 0xffffu), w0, ax); ay = fmaf(bf2f(p0 >> 16), w0, ay);
        ax = fmaf(bf2f(p1 & 0xffffu), w1, ax); ay = fmaf(bf2f(p1 >> 16), w1, ay);
        ax = fmaf(bf2f(p2 & 0xffffu), w2, ax); ay = fmaf(bf2f(p2 >> 16), w2, ay);
        ax = fmaf(bf2f(p3 & 0xffffu), w3, ax); ay = fmaf(bf2f(p3 >> 16), w3, ay);
    }
    for (; e < end; ++e) {
        int s0 = esrc[e];
        float w0 = enorm[e];
        uint32 p0 = hu[s0 * TPN + lane];
        ax = fmaf(bf2f(p0 & 0xffffu), w0, ax);
        ay = fmaf(bf2f(p0 >> 16), w0, ay);
    }
    *(float2*)&out[node * COLS + lane * 2] = make_float2(ax, ay);
}

// ---------------- BatchNorm stats ----------------
__global__ __launch_bounds__(256) void k_bn_stats(const float* __restrict__ x,
                                                  float* __restrict__ stats, int n) {
    const int f = threadIdx.x & 127;
    const int half = threadIdx.x >> 7;
    const int r0 = blockIdx.x * 512;
    float s = 0.f, s2 = 0.f;
    for (int j = 0; j < 256; ++j) {
        int r = r0 + half + 2 * j;
        if (r < n) {
            float v = x[r * 128 + f];
            s += v; s2 += v * v;
        }
    }
    atomicAdd(&stats[f], s);
    atomicAdd(&stats[128 + f], s2);
}

__global__ __launch_bounds__(128) void k_bn_final(const float* __restrict__ stats,
                                                  const float* __restrict__ gamma,
                                                  const float* __restrict__ beta,
                                                  float* __restrict__ ss, int n) {
    int f = threadIdx.x;
    float inv_n = 1.0f / (float)n;
    float mean = stats[f] * inv_n;
    float var = stats[128 + f] * inv_n - mean * mean;
    float scale = gamma[f] * rsqrtf(var + EPS_BN);
    ss[f] = scale;
    ss[128 + f] = beta[f] - mean * scale;
}

// ---------------- pool: sorted-batch run-length private accumulation ----------------
#define POOL_SLICE 128
__global__ __launch_bounds__(256) void k_pool2(const float* __restrict__ h3,
                                               const int* __restrict__ batch,
                                               float* __restrict__ sums,
                                               float* __restrict__ cnt, int n) {
    const int f = threadIdx.x & 31;
    const int sub = threadIdx.x >> 5;
    int node0 = blockIdx.x * (8 * POOL_SLICE) + sub * POOL_SLICE;
    if (node0 >= n) return;
    int node1 = min(node0 + POOL_SLICE, n);

    int cur_g = batch[node0];
    float acc = 0.f;
    float c = 0.f;
    for (int i = node0; i < node1; ++i) {
        int g = batch[i];
        if (g != cur_g) {
            atomicAdd(&sums[cur_g * 32 + f], acc);
            if (f == 0) atomicAdd(&cnt[cur_g], c);
            acc = 0.f; c = 0.f; cur_g = g;
        }
        acc += h3[i * 32 + f];
        c += 1.f;
    }
    atomicAdd(&sums[cur_g * 32 + f], acc);
    if (f == 0) atomicAdd(&cnt[cur_g], c);
}

__global__ __launch_bounds__(256) void k_final(const float* __restrict__ sums,
                                               const float* __restrict__ cnt,
                                               const float* __restrict__ b3,
                                               float* __restrict__ out) {
    int i = blockIdx.x * 256 + threadIdx.x;
    if (i >= NGRAPH * 32) return;
    int g = i >> 5;
    int f = i & 31;
    float c = fmaxf(cnt[g], 1.0f);
    float v = sums[i] / c + b3[f];
    out[i] = 1.0f / (1.0f + expf(-v));
}

// ---------------- launch ----------------
extern "C" void kernel_launch(void* const* d_in, const int* in_sizes, int n_in,
                              void* d_out, int out_size, void* d_ws, size_t ws_size,
                              hipStream_t stream) {
    const float* x      = (const float*)d_in[0];
    const int*   eidx   = (const int*)d_in[1];
    const int*   batch  = (const int*)d_in[2];
    const float* W1     = (const float*)d_in[3];
    const float* W2     = (const float*)d_in[5];
    const float* W3     = (const float*)d_in[7];
    const float* b3     = (const float*)d_in[8];
    const float* gamma1 = (const float*)d_in[9];
    const float* beta1  = (const float*)d_in[10];
    const float* gamma2 = (const float*)d_in[11];
    const float* beta2  = (const float*)d_in[12];

    const int N = in_sizes[0] / 128;
    const int E = in_sizes[1] / 2;
    const int* src = eidx;
    const int* dst = eidx + E;

    size_t off = 0;
    auto carve = [&](size_t bytes) {
        char* p = (char*)d_ws + off;
        off += (bytes + 511) & ~(size_t)511;
        return p;
    };
    const size_t NB = (size_t)N * 128 * sizeof(float);
    ushort16* bufA  = (ushort16*)carve(NB / 2);     // bf16 h (gather source)
    float* bufB     = (float*)carve(NB);            // fp32 agg output
    int*   cnt      = (int*)carve((size_t)N * 4);
    int*   rowstart = (int*)carve((size_t)N * 4);
    int*   fill     = (int*)carve((size_t)N * 4);
    float* dinv     = (float*)carve((size_t)N * 4);
    int*   esrc     = (int*)carve((size_t)E * 4);
    float* enorm    = (float*)carve((size_t)E * 4);
    float* stats    = (float*)carve(256 * 4);
    float* ss1      = (float*)carve(256 * 4);
    float* ss2      = (float*)carve(256 * 4);
    int*   blocksum = (int*)carve(1024 * 4);
    float* psum     = (float*)carve(NGRAPH * 32 * 4);
    float* pcnt     = (float*)carve(NGRAPH * 4);
    (void)ws_size; (void)n_in; (void)out_size;

    const int nblkN   = (N + 255) / 256;
    const int nblkE   = (E + 255) / 256;
    const int nbScan  = (N + 1023) / 1024;
    const int nblkAgg128 = ((size_t)N * 64 + 255) / 256;
    const int nblkAgg32  = ((size_t)N * 16 + 255) / 256;
    const int nblkPool   = (N + 8 * POOL_SLICE - 1) / (8 * POOL_SLICE);

    // --- CSR build ---
    hipMemsetAsync(cnt, 0, (size_t)N * 4, stream);
    hipMemsetAsync(fill, 0, (size_t)N * 4, stream);
    k_cnt<<<nblkE, 256, 0, stream>>>(dst, cnt, E);
    k_scan1<<<nbScan, 1024, 0, stream>>>(cnt, rowstart, blocksum, dinv, N);
    k_scan2<<<1, 1024, 0, stream>>>(blocksum, nbScan);
    k_scan3<<<nblkN, 256, 0, stream>>>(rowstart, blocksum, N);
    k_scatter<<<nblkE, 256, 0, stream>>>(src, dst, rowstart, fill, dinv, esrc, enorm, E);

    // --- layer 1 (b1 cancels under BN) ---
    k_gemm<128, 32, false><<<(N + 31) / 32, 256, 0, stream>>>(x, W1, nullptr, bufA, N);
    k_agg_csr<128><<<nblkAgg128, 256, 0, stream>>>(bufA, rowstart, cnt, esrc, enorm, dinv, bufB, N);
    hipMemsetAsync(stats, 0, 256 * 4, stream);
    k_bn_stats<<<(N + 511) / 512, 256, 0, stream>>>(bufB, stats, N);
    k_bn_final<<<1, 128, 0, stream>>>(stats, gamma1, beta1, ss1, N);

    // --- layer 2 (BN1+ReLU fused into A-staging) ---
    k_gemm<128, 32, true><<<(N + 31) / 32, 256, 0, stream>>>(bufB, W2, ss1, bufA, N);
    k_agg_csr<128><<<nblkAgg128, 256, 0, stream>>>(bufA, rowstart, cnt, esrc, enorm, dinv, bufB, N);
    hipMemsetAsync(stats, 0, 256 * 4, stream);
    k_bn_stats<<<(N + 511) / 512, 256, 0, stream>>>(bufB, stats, N);
    k_bn_final<<<1, 128, 0, stream>>>(stats, gamma2, beta2, ss2, N);

    // --- layer 3 (128 -> 32, BN2+ReLU fused) ---
    k_gemm<32, 128, true><<<(N + 127) / 128, 256, 0, stream>>>(bufB, W3, ss2, bufA, N);
    k_agg_csr<32><<<nblkAgg32, 256, 0, stream>>>(bufA, rowstart, cnt, esrc, enorm, dinv, bufB, N);

    // --- pool + sigmoid (b3 added post-pool) ---
    hipMemsetAsync(psum, 0, NGRAPH * 32 * 4, stream);
    hipMemsetAsync(pcnt, 0, NGRAPH * 4, stream);
    k_pool2<<<nblkPool, 256, 0, stream>>>(bufB, batch, psum, pcnt, N);
    k_final<<<(NGRAPH * 32 + 255) / 256, 256, 0, stream>>>(psum, pcnt, b3, (float*)d_out);
}

// Round 6
// 664.100 us; speedup vs baseline: 11.0295x; 1.1490x over previous
//
#include <hip/hip_runtime.h>
#include <math.h>

#define NGRAPH 64
#define EPS_BN 1e-5f

typedef unsigned int uint32;
typedef unsigned short ushort16;
typedef __attribute__((ext_vector_type(8))) short short8v;
typedef __attribute__((ext_vector_type(4))) float float4v;

__device__ __forceinline__ float bf2f(uint32 u16) {
    return __uint_as_float(u16 << 16);
}
__device__ __forceinline__ ushort16 f2bf(float f) {
    uint32 u = __float_as_uint(f);
    return (ushort16)((u + 0x7fffu + ((u >> 16) & 1u)) >> 16);  // RNE
}

// ---------------- degree histogram (int) ----------------
__global__ __launch_bounds__(256) void k_cnt(const int* __restrict__ dst, int* cnt, int ne) {
    int i = blockIdx.x * 256 + threadIdx.x;
    if (i < ne) atomicAdd(&cnt[dst[i]], 1);
}

// ---------------- hierarchical exclusive scan ----------------
__global__ __launch_bounds__(1024) void k_scan1(const int* __restrict__ cnt,
                                                int* __restrict__ rowstart,
                                                int* __restrict__ blocksum,
                                                float* __restrict__ dinv, int n) {
    __shared__ int sh[1024];
    const int tid = threadIdx.x;
    const int i = blockIdx.x * 1024 + tid;
    int v = (i < n) ? cnt[i] : 0;
    if (i < n) dinv[i] = rsqrtf((float)(v + 1));  // +1 self-loop, always > 0
    sh[tid] = v;
    __syncthreads();
    for (int off = 1; off < 1024; off <<= 1) {
        int t = (tid >= off) ? sh[tid - off] : 0;
        __syncthreads();
        sh[tid] += t;
        __syncthreads();
    }
    if (i < n) rowstart[i] = sh[tid] - v;  // exclusive in-block
    if (tid == 1023) blocksum[blockIdx.x] = sh[1023];
}

__global__ __launch_bounds__(1024) void k_scan2(int* __restrict__ blocksum, int nb) {
    __shared__ int sh[1024];
    const int tid = threadIdx.x;
    int v = (tid < nb) ? blocksum[tid] : 0;
    sh[tid] = v;
    __syncthreads();
    for (int off = 1; off < 1024; off <<= 1) {
        int t = (tid >= off) ? sh[tid - off] : 0;
        __syncthreads();
        sh[tid] += t;
        __syncthreads();
    }
    if (tid < nb) blocksum[tid] = sh[tid] - v;  // exclusive
}

__global__ __launch_bounds__(256) void k_scan3(int* __restrict__ rowstart,
                                               const int* __restrict__ blocksum, int n) {
    int i = blockIdx.x * 256 + threadIdx.x;
    if (i < n) rowstart[i] += blocksum[i >> 10];
}

// ---------------- scatter edges into CSR slots (src only; norm recomputed later) ----------------
__global__ __launch_bounds__(256) void k_scatter(const int* __restrict__ src,
                                                 const int* __restrict__ dst,
                                                 int* __restrict__ rowcur,
                                                 int* __restrict__ esrc, int ne) {
    int i = blockIdx.x * 256 + threadIdx.x;
    if (i >= ne) return;
    int s = src[i], d = dst[i];
    int pos = atomicAdd(&rowcur[d], 1);
    esrc[pos] = s;
}

// ---------------- W prep: Wt[c][k] = bf16(W[k][c]) ----------------
__global__ __launch_bounds__(256) void k_wprep(const float* __restrict__ W,
                                               ushort16* __restrict__ Wt,
                                               int rows, int cols) {
    int i = blockIdx.x * 256 + threadIdx.x;
    if (i >= rows * cols) return;
    int c = i / rows, k = i % rows;
    Wt[i] = f2bf(W[k * cols + c]);
}

// ---------------- MFMA GEMM: C(bf16) = act(A) @ W; A fp32, Wt bf16 [COLS][128] ----------------
// Block: 256 thr = 4 waves; 64 rows x COLS cols per block. mfma_f32_16x16x32_bf16.
template<int COLS, bool BN>
__global__ __launch_bounds__(256) void k_gemm_mfma(const float* __restrict__ A,
                                                   const ushort16* __restrict__ Wt,
                                                   const float* __restrict__ ss,
                                                   ushort16* __restrict__ C, int nrows) {
    constexpr int K = 128;
    constexpr int LDK = K + 8;  // pad 8 bf16 (16B): lane-row stride 272B -> 2-way banks (free)
    __shared__ ushort16 As[64 * LDK];
    __shared__ ushort16 Bs[COLS * LDK];
    const int tid = threadIdx.x;
    const int row0 = blockIdx.x * 64;

    // stage Wt -> Bs (16B chunks)
    {
        const uint4* wg = (const uint4*)Wt;
        for (int i = tid; i < COLS * (K / 8); i += 256) {
            int r = i >> 4, c8 = i & 15;
            *(uint4*)&Bs[r * LDK + c8 * 8] = wg[i];
        }
    }
    // stage A -> As with optional BN+ReLU, fp32 -> bf16
    for (int i = tid; i < 64 * (K / 4); i += 256) {
        int r = i >> 5, c4 = i & 31;
        float4 a;
        if (row0 + r < nrows) a = *(const float4*)&A[(size_t)(row0 + r) * K + c4 * 4];
        else a = make_float4(0.f, 0.f, 0.f, 0.f);
        if (BN) {
            float4 sc = *(const float4*)&ss[c4 * 4];
            float4 sh = *(const float4*)&ss[128 + c4 * 4];
            a.x = fmaxf(fmaf(a.x, sc.x, sh.x), 0.f);
            a.y = fmaxf(fmaf(a.y, sc.y, sh.y), 0.f);
            a.z = fmaxf(fmaf(a.z, sc.z, sh.z), 0.f);
            a.w = fmaxf(fmaf(a.w, sc.w, sh.w), 0.f);
        }
        ushort4 o;
        o.x = f2bf(a.x); o.y = f2bf(a.y); o.z = f2bf(a.z); o.w = f2bf(a.w);
        *(ushort4*)&As[r * LDK + c4 * 4] = o;
    }
    __syncthreads();

    const int w = tid >> 6;        // wave 0..3 -> rows w*16..w*16+15
    const int l = tid & 63;
    const int lr = l & 15;         // A row / B col within tile
    const int lg = l >> 4;         // k-group
    constexpr int CT = COLS / 16;

    float4v acc[CT] = {};
    short8v afrag[4];
    #pragma unroll
    for (int kk = 0; kk < 4; ++kk)
        afrag[kk] = *(const short8v*)&As[(w * 16 + lr) * LDK + kk * 32 + lg * 8];
    #pragma unroll
    for (int kk = 0; kk < 4; ++kk) {
        #pragma unroll
        for (int ct = 0; ct < CT; ++ct) {
            short8v b = *(const short8v*)&Bs[(ct * 16 + lr) * LDK + kk * 32 + lg * 8];
            acc[ct] = __builtin_amdgcn_mfma_f32_16x16x32_bf16(afrag[kk], b, acc[ct], 0, 0, 0);
        }
    }
    // store: C[row0 + w*16 + lg*4 + r][ct*16 + lr]
    #pragma unroll
    for (int ct = 0; ct < CT; ++ct) {
        #pragma unroll
        for (int r = 0; r < 4; ++r) {
            int gr = row0 + w * 16 + lg * 4 + r;
            if (gr < nrows) C[(size_t)gr * COLS + ct * 16 + lr] = f2bf(acc[ct][r]);
        }
    }
}

// ---------------- CSR aggregation (bf16 gather, fp32 accum, norm on the fly) ----------------
template<int COLS>
__global__ __launch_bounds__(256) void k_agg_csr(const ushort16* __restrict__ h,
                                                 const int* __restrict__ rowstart,
                                                 const int* __restrict__ cnt,
                                                 const int* __restrict__ esrc,
                                                 const float* __restrict__ dinv,
                                                 float* __restrict__ out, int n) {
    constexpr int TPN = COLS / 2;  // threads per node, 2 bf16 (one uint) each
    const uint32* __restrict__ hu = (const uint32*)h;
    int gt = blockIdx.x * 256 + threadIdx.x;
    int node = gt / TPN;
    if (node >= n) return;
    int lane = gt % TPN;

    float di = dinv[node];
    uint32 p = hu[(size_t)node * TPN + lane];
    float ax = bf2f(p & 0xffffu) * di * di;
    float ay = bf2f(p >> 16) * di * di;

    const int beg = rowstart[node];
    const int end = beg + cnt[node];
    int e = beg;
    for (; e + 4 <= end; e += 4) {
        int s0 = esrc[e], s1 = esrc[e + 1], s2 = esrc[e + 2], s3 = esrc[e + 3];
        float w0 = dinv[s0] * di, w1 = dinv[s1] * di;
        float w2 = dinv[s2] * di, w3 = dinv[s3] * di;
        uint32 p0 = hu[(size_t)s0 * TPN + lane];
        uint32 p1 = hu[(size_t)s1 * TPN + lane];
        uint32 p2 = hu[(size_t)s2 * TPN + lane];
        uint32 p3 = hu[(size_t)s3 * TPN + lane];
        ax = fmaf(bf2f(p0 & 0xffffu), w0, ax); ay = fmaf(bf2f(p0 >> 16), w0, ay);
        ax = fmaf(bf2f(p1 & 0xffffu), w1, ax); ay = fmaf(bf2f(p1 >> 16), w1, ay);
        ax = fmaf(bf2f(p2 & 0xffffu), w2, ax); ay = fmaf(bf2f(p2 >> 16), w2, ay);
        ax = fmaf(bf2f(p3 & 0xffffu), w3, ax); ay = fmaf(bf2f(p3 >> 16), w3, ay);
    }
    for (; e < end; ++e) {
        int s0 = esrc[e];
        float w0 = dinv[s0] * di;
        uint32 p0 = hu[(size_t)s0 * TPN + lane];
        ax = fmaf(bf2f(p0 & 0xffffu), w0, ax);
        ay = fmaf(bf2f(p0 >> 16), w0, ay);
    }
    *(float2*)&out[(size_t)node * COLS + lane * 2] = make_float2(ax, ay);
}

// ---------------- BatchNorm stats ----------------
__global__ __launch_bounds__(256) void k_bn_stats(const float* __restrict__ x,
                                                  float* __restrict__ stats, int n) {
    const int f = threadIdx.x & 127;
    const int half = threadIdx.x >> 7;
    const int r0 = blockIdx.x * 512;
    float s = 0.f, s2 = 0.f;
    for (int j = 0; j < 256; ++j) {
        int r = r0 + half + 2 * j;
        if (r < n) {
            float v = x[r * 128 + f];
            s += v; s2 += v * v;
        }
    }
    atomicAdd(&stats[f], s);
    atomicAdd(&stats[128 + f], s2);
}

__global__ __launch_bounds__(128) void k_bn_final(const float* __restrict__ stats,
                                                  const float* __restrict__ gamma,
                                                  const float* __restrict__ beta,
                                                  float* __restrict__ ss, int n) {
    int f = threadIdx.x;
    float inv_n = 1.0f / (float)n;
    float mean = stats[f] * inv_n;
    float var = stats[128 + f] * inv_n - mean * mean;
    float scale = gamma[f] * rsqrtf(var + EPS_BN);
    ss[f] = scale;
    ss[128 + f] = beta[f] - mean * scale;
}

// ---------------- pool: sorted-batch run-length private accumulation ----------------
#define POOL_SLICE 128
__global__ __launch_bounds__(256) void k_pool2(const float* __restrict__ h3,
                                               const int* __restrict__ batch,
                                               float* __restrict__ sums,
                                               float* __restrict__ cnt, int n) {
    const int f = threadIdx.x & 31;
    const int sub = threadIdx.x >> 5;
    int node0 = blockIdx.x * (8 * POOL_SLICE) + sub * POOL_SLICE;
    if (node0 >= n) return;
    int node1 = min(node0 + POOL_SLICE, n);

    int cur_g = batch[node0];
    float acc = 0.f;
    float c = 0.f;
    for (int i = node0; i < node1; ++i) {
        int g = batch[i];
        if (g != cur_g) {
            atomicAdd(&sums[cur_g * 32 + f], acc);
            if (f == 0) atomicAdd(&cnt[cur_g], c);
            acc = 0.f; c = 0.f; cur_g = g;
        }
        acc += h3[i * 32 + f];
        c += 1.f;
    }
    atomicAdd(&sums[cur_g * 32 + f], acc);
    if (f == 0) atomicAdd(&cnt[cur_g], c);
}

__global__ __launch_bounds__(256) void k_final(const float* __restrict__ sums,
                                               const float* __restrict__ cnt,
                                               const float* __restrict__ b3,
                                               float* __restrict__ out) {
    int i = blockIdx.x * 256 + threadIdx.x;
    if (i >= NGRAPH * 32) return;
    int g = i >> 5;
    int f = i & 31;
    float c = fmaxf(cnt[g], 1.0f);
    float v = sums[i] / c + b3[f];
    out[i] = 1.0f / (1.0f + expf(-v));
}

// ---------------- launch ----------------
extern "C" void kernel_launch(void* const* d_in, const int* in_sizes, int n_in,
                              void* d_out, int out_size, void* d_ws, size_t ws_size,
                              hipStream_t stream) {
    const float* x      = (const float*)d_in[0];
    const int*   eidx   = (const int*)d_in[1];
    const int*   batch  = (const int*)d_in[2];
    const float* W1     = (const float*)d_in[3];
    const float* W2     = (const float*)d_in[5];
    const float* W3     = (const float*)d_in[7];
    const float* b3     = (const float*)d_in[8];
    const float* gamma1 = (const float*)d_in[9];
    const float* beta1  = (const float*)d_in[10];
    const float* gamma2 = (const float*)d_in[11];
    const float* beta2  = (const float*)d_in[12];

    const int N = in_sizes[0] / 128;
    const int E = in_sizes[1] / 2;
    const int* src = eidx;
    const int* dst = eidx + E;

    size_t off = 0;
    auto carve = [&](size_t bytes) {
        char* p = (char*)d_ws + off;
        off += (bytes + 511) & ~(size_t)511;
        return p;
    };
    const size_t NB = (size_t)N * 128 * sizeof(float);
    ushort16* bufA  = (ushort16*)carve(NB / 2);     // bf16 h (gather source)
    float* bufB     = (float*)carve(NB);            // fp32 agg output
    int*   cnt      = (int*)carve((size_t)N * 4);
    int*   rowstart = (int*)carve((size_t)N * 4);
    int*   rowcur   = (int*)carve((size_t)N * 4);
    float* dinv     = (float*)carve((size_t)N * 4);
    int*   esrc     = (int*)carve((size_t)E * 4);
    ushort16* wt1   = (ushort16*)carve(128 * 128 * 2);
    ushort16* wt2   = (ushort16*)carve(128 * 128 * 2);
    ushort16* wt3   = (ushort16*)carve(32 * 128 * 2);
    float* stats    = (float*)carve(256 * 4);
    float* ss1      = (float*)carve(256 * 4);
    float* ss2      = (float*)carve(256 * 4);
    int*   blocksum = (int*)carve(1024 * 4);
    float* psum     = (float*)carve(NGRAPH * 32 * 4);
    float* pcnt     = (float*)carve(NGRAPH * 4);
    (void)ws_size; (void)n_in; (void)out_size;

    const int nblkN   = (N + 255) / 256;
    const int nblkE   = (E + 255) / 256;
    const int nbScan  = (N + 1023) / 1024;
    const int nbGemm  = (N + 63) / 64;
    const int nblkAgg128 = ((size_t)N * 64 + 255) / 256;
    const int nblkAgg32  = ((size_t)N * 16 + 255) / 256;
    const int nblkPool   = (N + 8 * POOL_SLICE - 1) / (8 * POOL_SLICE);

    // --- W prep (bf16, transposed) ---
    k_wprep<<<(128 * 128 + 255) / 256, 256, 0, stream>>>(W1, wt1, 128, 128);
    k_wprep<<<(128 * 128 + 255) / 256, 256, 0, stream>>>(W2, wt2, 128, 128);
    k_wprep<<<(32 * 128 + 255) / 256, 256, 0, stream>>>(W3, wt3, 128, 32);

    // --- CSR build ---
    hipMemsetAsync(cnt, 0, (size_t)N * 4, stream);
    k_cnt<<<nblkE, 256, 0, stream>>>(dst, cnt, E);
    k_scan1<<<nbScan, 1024, 0, stream>>>(cnt, rowstart, blocksum, dinv, N);
    k_scan2<<<1, 1024, 0, stream>>>(blocksum, nbScan);
    k_scan3<<<nblkN, 256, 0, stream>>>(rowstart, blocksum, N);
    hipMemcpyAsync(rowcur, rowstart, (size_t)N * 4, hipMemcpyDeviceToDevice, stream);
    k_scatter<<<nblkE, 256, 0, stream>>>(src, dst, rowcur, esrc, E);

    // --- layer 1 (b1 cancels under BN) ---
    k_gemm_mfma<128, false><<<nbGemm, 256, 0, stream>>>(x, wt1, nullptr, bufA, N);
    k_agg_csr<128><<<nblkAgg128, 256, 0, stream>>>(bufA, rowstart, cnt, esrc, dinv, bufB, N);
    hipMemsetAsync(stats, 0, 256 * 4, stream);
    k_bn_stats<<<(N + 511) / 512, 256, 0, stream>>>(bufB, stats, N);
    k_bn_final<<<1, 128, 0, stream>>>(stats, gamma1, beta1, ss1, N);

    // --- layer 2 (BN1+ReLU fused into A-staging) ---
    k_gemm_mfma<128, true><<<nbGemm, 256, 0, stream>>>(bufB, wt2, ss1, bufA, N);
    k_agg_csr<128><<<nblkAgg128, 256, 0, stream>>>(bufA, rowstart, cnt, esrc, dinv, bufB, N);
    hipMemsetAsync(stats, 0, 256 * 4, stream);
    k_bn_stats<<<(N + 511) / 512, 256, 0, stream>>>(bufB, stats, N);
    k_bn_final<<<1, 128, 0, stream>>>(stats, gamma2, beta2, ss2, N);

    // --- layer 3 (128 -> 32, BN2+ReLU fused) ---
    k_gemm_mfma<32, true><<<nbGemm, 256, 0, stream>>>(bufB, wt3, ss2, bufA, N);
    k_agg_csr<32><<<nblkAgg32, 256, 0, stream>>>(bufA, rowstart, cnt, esrc, dinv, bufB, N);

    // --- pool + sigmoid (b3 added post-pool) ---
    hipMemsetAsync(psum, 0, NGRAPH * 32 * 4, stream);
    hipMemsetAsync(pcnt, 0, NGRAPH * 4, stream);
    k_pool2<<<nblkPool, 256, 0, stream>>>(bufB, batch, psum, pcnt, N);
    k_final<<<(NGRAPH * 32 + 255) / 256, 256, 0, stream>>>(psum, pcnt, b3, (float*)d_out);
}

// Round 7
// 604.633 us; speedup vs baseline: 12.1143x; 1.0984x over previous
//
#include <hip/hip_runtime.h>
#include <math.h>

#define NGRAPH 64
#define EPS_BN 1e-5f

typedef unsigned int uint32;
typedef unsigned short ushort16;
typedef __attribute__((ext_vector_type(8))) short short8v;
typedef __attribute__((ext_vector_type(4))) float float4v;

__device__ __forceinline__ float bf2f(uint32 u16) {
    return __uint_as_float(u16 << 16);
}
__device__ __forceinline__ ushort16 f2bf(float f) {
    uint32 u = __float_as_uint(f);
    return (ushort16)((u + 0x7fffu + ((u >> 16) & 1u)) >> 16);  // RNE
}

// ---------------- degree histogram (int) ----------------
__global__ __launch_bounds__(256) void k_cnt(const int* __restrict__ dst, int* cnt, int ne) {
    int i = blockIdx.x * 256 + threadIdx.x;
    if (i < ne) atomicAdd(&cnt[dst[i]], 1);
}

// ---------------- hierarchical exclusive scan ----------------
__global__ __launch_bounds__(1024) void k_scan1(const int* __restrict__ cnt,
                                                int* __restrict__ rowstart,
                                                int* __restrict__ blocksum,
                                                float* __restrict__ dinv, int n) {
    __shared__ int sh[1024];
    const int tid = threadIdx.x;
    const int i = blockIdx.x * 1024 + tid;
    int v = (i < n) ? cnt[i] : 0;
    if (i < n) dinv[i] = rsqrtf((float)(v + 1));  // +1 self-loop, always > 0
    sh[tid] = v;
    __syncthreads();
    for (int off = 1; off < 1024; off <<= 1) {
        int t = (tid >= off) ? sh[tid - off] : 0;
        __syncthreads();
        sh[tid] += t;
        __syncthreads();
    }
    if (i < n) rowstart[i] = sh[tid] - v;  // exclusive in-block
    if (tid == 1023) blocksum[blockIdx.x] = sh[1023];
}

__global__ __launch_bounds__(1024) void k_scan2(int* __restrict__ blocksum, int nb) {
    __shared__ int sh[1024];
    const int tid = threadIdx.x;
    int v = (tid < nb) ? blocksum[tid] : 0;
    sh[tid] = v;
    __syncthreads();
    for (int off = 1; off < 1024; off <<= 1) {
        int t = (tid >= off) ? sh[tid - off] : 0;
        __syncthreads();
        sh[tid] += t;
        __syncthreads();
    }
    if (tid < nb) blocksum[tid] = sh[tid] - v;  // exclusive
}

// scan3: add block offsets; also initialize rowcur = rowstart (for scatter fill).
__global__ __launch_bounds__(256) void k_scan3(int* __restrict__ rowstart,
                                               int* __restrict__ rowcur,
                                               const int* __restrict__ blocksum, int n) {
    int i = blockIdx.x * 256 + threadIdx.x;
    if (i < n) {
        int v = rowstart[i] + blocksum[i >> 10];
        rowstart[i] = v;
        rowcur[i] = v;
    }
}

// ---------------- XCD-windowed scatter: blocks with bid%8==w handle dst-window w ----------------
// Window w covers dst in [w*wsz, (w+1)*wsz). Consecutive bids round-robin across the
// 8 XCDs, so each esrc/rowcur line is (in practice) written through one XCD's L2 ->
// dense writebacks instead of one 64B line per 4B store. Correct regardless of mapping.
#define SC_EPB 8
__global__ __launch_bounds__(256) void k_scatter_w(const int* __restrict__ src,
                                                   const int* __restrict__ dst,
                                                   int* __restrict__ rowcur,
                                                   int* __restrict__ esrc,
                                                   int ne, int wsz) {
    const int w = blockIdx.x & 7;
    const int chunk = blockIdx.x >> 3;
    const int wlo = w * wsz;
    const int whi = wlo + wsz;
    int base = chunk * (256 * SC_EPB) + threadIdx.x;
    #pragma unroll
    for (int j = 0; j < SC_EPB; ++j) {
        int i = base + j * 256;
        if (i < ne) {
            int d = dst[i];
            if (d >= wlo && d < whi) {
                int pos = atomicAdd(&rowcur[d], 1);
                esrc[pos] = src[i];
            }
        }
    }
}

// ---------------- W prep: Wt[c][k] = bf16(W[k][c]) ----------------
__global__ __launch_bounds__(256) void k_wprep(const float* __restrict__ W,
                                               ushort16* __restrict__ Wt,
                                               int rows, int cols) {
    int i = blockIdx.x * 256 + threadIdx.x;
    if (i >= rows * cols) return;
    int c = i / rows, k = i % rows;
    Wt[i] = f2bf(W[k * cols + c]);
}

// ---------------- MFMA GEMM: C(bf16) = act(A) @ W; A fp32, Wt bf16 [COLS][128] ----------------
template<int COLS, bool BN>
__global__ __launch_bounds__(256) void k_gemm_mfma(const float* __restrict__ A,
                                                   const ushort16* __restrict__ Wt,
                                                   const float* __restrict__ ss,
                                                   ushort16* __restrict__ C, int nrows) {
    constexpr int K = 128;
    constexpr int LDK = K + 8;  // pad 16B: lane-row stride 272B -> 2-way banks (free)
    __shared__ ushort16 As[64 * LDK];
    __shared__ ushort16 Bs[COLS * LDK];
    const int tid = threadIdx.x;
    const int row0 = blockIdx.x * 64;

    {
        const uint4* wg = (const uint4*)Wt;
        for (int i = tid; i < COLS * (K / 8); i += 256) {
            int r = i >> 4, c8 = i & 15;
            *(uint4*)&Bs[r * LDK + c8 * 8] = wg[i];
        }
    }
    for (int i = tid; i < 64 * (K / 4); i += 256) {
        int r = i >> 5, c4 = i & 31;
        float4 a;
        if (row0 + r < nrows) a = *(const float4*)&A[(size_t)(row0 + r) * K + c4 * 4];
        else a = make_float4(0.f, 0.f, 0.f, 0.f);
        if (BN) {
            float4 sc = *(const float4*)&ss[c4 * 4];
            float4 sh = *(const float4*)&ss[128 + c4 * 4];
            a.x = fmaxf(fmaf(a.x, sc.x, sh.x), 0.f);
            a.y = fmaxf(fmaf(a.y, sc.y, sh.y), 0.f);
            a.z = fmaxf(fmaf(a.z, sc.z, sh.z), 0.f);
            a.w = fmaxf(fmaf(a.w, sc.w, sh.w), 0.f);
        }
        ushort4 o;
        o.x = f2bf(a.x); o.y = f2bf(a.y); o.z = f2bf(a.z); o.w = f2bf(a.w);
        *(ushort4*)&As[r * LDK + c4 * 4] = o;
    }
    __syncthreads();

    const int w = tid >> 6;
    const int l = tid & 63;
    const int lr = l & 15;
    const int lg = l >> 4;
    constexpr int CT = COLS / 16;

    float4v acc[CT] = {};
    short8v afrag[4];
    #pragma unroll
    for (int kk = 0; kk < 4; ++kk)
        afrag[kk] = *(const short8v*)&As[(w * 16 + lr) * LDK + kk * 32 + lg * 8];
    #pragma unroll
    for (int kk = 0; kk < 4; ++kk) {
        #pragma unroll
        for (int ct = 0; ct < CT; ++ct) {
            short8v b = *(const short8v*)&Bs[(ct * 16 + lr) * LDK + kk * 32 + lg * 8];
            acc[ct] = __builtin_amdgcn_mfma_f32_16x16x32_bf16(afrag[kk], b, acc[ct], 0, 0, 0);
        }
    }
    #pragma unroll
    for (int ct = 0; ct < CT; ++ct) {
        #pragma unroll
        for (int r = 0; r < 4; ++r) {
            int gr = row0 + w * 16 + lg * 4 + r;
            if (gr < nrows) C[(size_t)gr * COLS + ct * 16 + lr] = f2bf(acc[ct][r]);
        }
    }
}

// ---------------- CSR aggregation (bf16 gather, fp32 accum, norm on the fly) ----------------
template<int COLS>
__global__ __launch_bounds__(256) void k_agg_csr(const ushort16* __restrict__ h,
                                                 const int* __restrict__ rowstart,
                                                 const int* __restrict__ cnt,
                                                 const int* __restrict__ esrc,
                                                 const float* __restrict__ dinv,
                                                 float* __restrict__ out, int n) {
    constexpr int TPN = COLS / 2;
    const uint32* __restrict__ hu = (const uint32*)h;
    int gt = blockIdx.x * 256 + threadIdx.x;
    int node = gt / TPN;
    if (node >= n) return;
    int lane = gt % TPN;

    float di = dinv[node];
    uint32 p = hu[(size_t)node * TPN + lane];
    float ax = bf2f(p & 0xffffu) * di * di;
    float ay = bf2f(p >> 16) * di * di;

    const int beg = rowstart[node];
    const int end = beg + cnt[node];
    int e = beg;
    for (; e + 4 <= end; e += 4) {
        int s0 = esrc[e], s1 = esrc[e + 1], s2 = esrc[e + 2], s3 = esrc[e + 3];
        float w0 = dinv[s0] * di, w1 = dinv[s1] * di;
        float w2 = dinv[s2] * di, w3 = dinv[s3] * di;
        uint32 p0 = hu[(size_t)s0 * TPN + lane];
        uint32 p1 = hu[(size_t)s1 * TPN + lane];
        uint32 p2 = hu[(size_t)s2 * TPN + lane];
        uint32 p3 = hu[(size_t)s3 * TPN + lane];
        ax = fmaf(bf2f(p0 & 0xffffu), w0, ax); ay = fmaf(bf2f(p0 >> 16), w0, ay);
        ax = fmaf(bf2f(p1 & 0xffffu), w1, ax); ay = fmaf(bf2f(p1 >> 16), w1, ay);
        ax = fmaf(bf2f(p2 & 0xffffu), w2, ax); ay = fmaf(bf2f(p2 >> 16), w2, ay);
        ax = fmaf(bf2f(p3 & 0xffffu), w3, ax); ay = fmaf(bf2f(p3 >> 16), w3, ay);
    }
    for (; e < end; ++e) {
        int s0 = esrc[e];
        float w0 = dinv[s0] * di;
        uint32 p0 = hu[(size_t)s0 * TPN + lane];
        ax = fmaf(bf2f(p0 & 0xffffu), w0, ax);
        ay = fmaf(bf2f(p0 >> 16), w0, ay);
    }
    *(float2*)&out[(size_t)node * COLS + lane * 2] = make_float2(ax, ay);
}

// ---------------- BatchNorm stats ----------------
__global__ __launch_bounds__(256) void k_bn_stats(const float* __restrict__ x,
                                                  float* __restrict__ stats, int n) {
    const int f = threadIdx.x & 127;
    const int half = threadIdx.x >> 7;
    const int r0 = blockIdx.x * 512;
    float s = 0.f, s2 = 0.f;
    for (int j = 0; j < 256; ++j) {
        int r = r0 + half + 2 * j;
        if (r < n) {
            float v = x[r * 128 + f];
            s += v; s2 += v * v;
        }
    }
    atomicAdd(&stats[f], s);
    atomicAdd(&stats[128 + f], s2);
}

__global__ __launch_bounds__(128) void k_bn_final(const float* __restrict__ stats,
                                                  const float* __restrict__ gamma,
                                                  const float* __restrict__ beta,
                                                  float* __restrict__ ss, int n) {
    int f = threadIdx.x;
    float inv_n = 1.0f / (float)n;
    float mean = stats[f] * inv_n;
    float var = stats[128 + f] * inv_n - mean * mean;
    float scale = gamma[f] * rsqrtf(var + EPS_BN);
    ss[f] = scale;
    ss[128 + f] = beta[f] - mean * scale;
}

// ---------------- pool: sorted-batch run-length private accumulation ----------------
#define POOL_SLICE 128
__global__ __launch_bounds__(256) void k_pool2(const float* __restrict__ h3,
                                               const int* __restrict__ batch,
                                               float* __restrict__ sums,
                                               float* __restrict__ cnt, int n) {
    const int f = threadIdx.x & 31;
    const int sub = threadIdx.x >> 5;
    int node0 = blockIdx.x * (8 * POOL_SLICE) + sub * POOL_SLICE;
    if (node0 >= n) return;
    int node1 = min(node0 + POOL_SLICE, n);

    int cur_g = batch[node0];
    float acc = 0.f;
    float c = 0.f;
    for (int i = node0; i < node1; ++i) {
        int g = batch[i];
        if (g != cur_g) {
            atomicAdd(&sums[cur_g * 32 + f], acc);
            if (f == 0) atomicAdd(&cnt[cur_g], c);
            acc = 0.f; c = 0.f; cur_g = g;
        }
        acc += h3[i * 32 + f];
        c += 1.f;
    }
    atomicAdd(&sums[cur_g * 32 + f], acc);
    if (f == 0) atomicAdd(&cnt[cur_g], c);
}

__global__ __launch_bounds__(256) void k_final(const float* __restrict__ sums,
                                               const float* __restrict__ cnt,
                                               const float* __restrict__ b3,
                                               float* __restrict__ out) {
    int i = blockIdx.x * 256 + threadIdx.x;
    if (i >= NGRAPH * 32) return;
    int g = i >> 5;
    int f = i & 31;
    float c = fmaxf(cnt[g], 1.0f);
    float v = sums[i] / c + b3[f];
    out[i] = 1.0f / (1.0f + expf(-v));
}

// ---------------- launch ----------------
extern "C" void kernel_launch(void* const* d_in, const int* in_sizes, int n_in,
                              void* d_out, int out_size, void* d_ws, size_t ws_size,
                              hipStream_t stream) {
    const float* x      = (const float*)d_in[0];
    const int*   eidx   = (const int*)d_in[1];
    const int*   batch  = (const int*)d_in[2];
    const float* W1     = (const float*)d_in[3];
    const float* W2     = (const float*)d_in[5];
    const float* W3     = (const float*)d_in[7];
    const float* b3     = (const float*)d_in[8];
    const float* gamma1 = (const float*)d_in[9];
    const float* beta1  = (const float*)d_in[10];
    const float* gamma2 = (const float*)d_in[11];
    const float* beta2  = (const float*)d_in[12];

    const int N = in_sizes[0] / 128;
    const int E = in_sizes[1] / 2;
    const int* src = eidx;
    const int* dst = eidx + E;

    size_t off = 0;
    auto carve = [&](size_t bytes) {
        char* p = (char*)d_ws + off;
        off += (bytes + 511) & ~(size_t)511;
        return p;
    };
    const size_t NB = (size_t)N * 128 * sizeof(float);
    ushort16* bufA  = (ushort16*)carve(NB / 2);     // bf16 h (gather source)
    float* bufB     = (float*)carve(NB);            // fp32 agg output
    int*   cnt      = (int*)carve((size_t)N * 4);
    int*   rowstart = (int*)carve((size_t)N * 4);
    int*   rowcur   = (int*)carve((size_t)N * 4);
    float* dinv     = (float*)carve((size_t)N * 4);
    int*   esrc     = (int*)carve((size_t)E * 4);
    ushort16* wt1   = (ushort16*)carve(128 * 128 * 2);
    ushort16* wt2   = (ushort16*)carve(128 * 128 * 2);
    ushort16* wt3   = (ushort16*)carve(32 * 128 * 2);
    float* stats    = (float*)carve(256 * 4);
    float* ss1      = (float*)carve(256 * 4);
    float* ss2      = (float*)carve(256 * 4);
    int*   blocksum = (int*)carve(1024 * 4);
    float* psum     = (float*)carve(NGRAPH * 32 * 4);
    float* pcnt     = (float*)carve(NGRAPH * 4);
    (void)ws_size; (void)n_in; (void)out_size;

    const int nblkN   = (N + 255) / 256;
    const int nblkE   = (E + 255) / 256;
    const int nbScan  = (N + 1023) / 1024;
    const int nbGemm  = (N + 63) / 64;
    const int nblkAgg128 = ((size_t)N * 64 + 255) / 256;
    const int nblkAgg32  = ((size_t)N * 16 + 255) / 256;
    const int nblkPool   = (N + 8 * POOL_SLICE - 1) / (8 * POOL_SLICE);
    const int wsz        = (N + 7) / 8;                       // dst window size
    const int nbScat     = ((E + 256 * SC_EPB - 1) / (256 * SC_EPB)) * 8;

    // --- W prep (bf16, transposed) ---
    k_wprep<<<(128 * 128 + 255) / 256, 256, 0, stream>>>(W1, wt1, 128, 128);
    k_wprep<<<(128 * 128 + 255) / 256, 256, 0, stream>>>(W2, wt2, 128, 128);
    k_wprep<<<(32 * 128 + 255) / 256, 256, 0, stream>>>(W3, wt3, 128, 32);

    // --- CSR build ---
    hipMemsetAsync(cnt, 0, (size_t)N * 4, stream);
    k_cnt<<<nblkE, 256, 0, stream>>>(dst, cnt, E);
    k_scan1<<<nbScan, 1024, 0, stream>>>(cnt, rowstart, blocksum, dinv, N);
    k_scan2<<<1, 1024, 0, stream>>>(blocksum, nbScan);
    k_scan3<<<nblkN, 256, 0, stream>>>(rowstart, rowcur, blocksum, N);
    k_scatter_w<<<nbScat, 256, 0, stream>>>(src, dst, rowcur, esrc, E, wsz);

    // --- layer 1 (b1 cancels under BN) ---
    k_gemm_mfma<128, false><<<nbGemm, 256, 0, stream>>>(x, wt1, nullptr, bufA, N);
    k_agg_csr<128><<<nblkAgg128, 256, 0, stream>>>(bufA, rowstart, cnt, esrc, dinv, bufB, N);
    hipMemsetAsync(stats, 0, 256 * 4, stream);
    k_bn_stats<<<(N + 511) / 512, 256, 0, stream>>>(bufB, stats, N);
    k_bn_final<<<1, 128, 0, stream>>>(stats, gamma1, beta1, ss1, N);

    // --- layer 2 (BN1+ReLU fused into A-staging) ---
    k_gemm_mfma<128, true><<<nbGemm, 256, 0, stream>>>(bufB, wt2, ss1, bufA, N);
    k_agg_csr<128><<<nblkAgg128, 256, 0, stream>>>(bufA, rowstart, cnt, esrc, dinv, bufB, N);
    hipMemsetAsync(stats, 0, 256 * 4, stream);
    k_bn_stats<<<(N + 511) / 512, 256, 0, stream>>>(bufB, stats, N);
    k_bn_final<<<1, 128, 0, stream>>>(stats, gamma2, beta2, ss2, N);

    // --- layer 3 (128 -> 32, BN2+ReLU fused) ---
    k_gemm_mfma<32, true><<<nbGemm, 256, 0, stream>>>(bufB, wt3, ss2, bufA, N);
    k_agg_csr<32><<<nblkAgg32, 256, 0, stream>>>(bufA, rowstart, cnt, esrc, dinv, bufB, N);

    // --- pool + sigmoid (b3 added post-pool) ---
    hipMemsetAsync(psum, 0, NGRAPH * 32 * 4, stream);
    hipMemsetAsync(pcnt, 0, NGRAPH * 4, stream);
    k_pool2<<<nblkPool, 256, 0, stream>>>(bufB, batch, psum, pcnt, N);
    k_final<<<(NGRAPH * 32 + 255) / 256, 256, 0, stream>>>(psum, pcnt, b3, (float*)d_out);
}

// Round 8
// 476.992 us; speedup vs baseline: 15.3561x; 1.2676x over previous
//
#include <hip/hip_runtime.h>
#include <math.h>

#define NGRAPH 64
#define EPS_BN 1e-5f
#define BN_BLOCKS 512

typedef unsigned int uint32;
typedef unsigned short ushort16;
typedef __attribute__((ext_vector_type(8))) short short8v;
typedef __attribute__((ext_vector_type(4))) float float4v;

__device__ __forceinline__ float bf2f(uint32 u16) {
    return __uint_as_float(u16 << 16);
}
__device__ __forceinline__ ushort16 f2bf(float f) {
    uint32 u = __float_as_uint(f);
    return (ushort16)((u + 0x7fffu + ((u >> 16) & 1u)) >> 16);  // RNE
}
__device__ __forceinline__ uint32 pack2(float lo, float hi) {
    return (uint32)f2bf(lo) | ((uint32)f2bf(hi) << 16);
}

// ---------------- degree histogram (int) ----------------
__global__ __launch_bounds__(256) void k_cnt(const int* __restrict__ dst, int* cnt, int ne) {
    int i = blockIdx.x * 256 + threadIdx.x;
    if (i < ne) atomicAdd(&cnt[dst[i]], 1);
}

// ---------------- hierarchical exclusive scan ----------------
__global__ __launch_bounds__(1024) void k_scan1(const int* __restrict__ cnt,
                                                int* __restrict__ rowstart,
                                                int* __restrict__ blocksum,
                                                float* __restrict__ dinv, int n) {
    __shared__ int sh[1024];
    const int tid = threadIdx.x;
    const int i = blockIdx.x * 1024 + tid;
    int v = (i < n) ? cnt[i] : 0;
    if (i < n) dinv[i] = rsqrtf((float)(v + 1));  // +1 self-loop, always > 0
    sh[tid] = v;
    __syncthreads();
    for (int off = 1; off < 1024; off <<= 1) {
        int t = (tid >= off) ? sh[tid - off] : 0;
        __syncthreads();
        sh[tid] += t;
        __syncthreads();
    }
    if (i < n) rowstart[i] = sh[tid] - v;  // exclusive in-block
    if (tid == 1023) blocksum[blockIdx.x] = sh[1023];
}

__global__ __launch_bounds__(1024) void k_scan2(int* __restrict__ blocksum, int nb) {
    __shared__ int sh[1024];
    const int tid = threadIdx.x;
    int v = (tid < nb) ? blocksum[tid] : 0;
    sh[tid] = v;
    __syncthreads();
    for (int off = 1; off < 1024; off <<= 1) {
        int t = (tid >= off) ? sh[tid - off] : 0;
        __syncthreads();
        sh[tid] += t;
        __syncthreads();
    }
    if (tid < nb) blocksum[tid] = sh[tid] - v;  // exclusive
}

__global__ __launch_bounds__(256) void k_scan3(int* __restrict__ rowstart,
                                               int* __restrict__ rowcur,
                                               const int* __restrict__ blocksum, int n) {
    int i = blockIdx.x * 256 + threadIdx.x;
    if (i < n) {
        int v = rowstart[i] + blocksum[i >> 10];
        rowstart[i] = v;
        rowcur[i] = v;
    }
}

// ---------------- XCD-windowed scatter ----------------
#define SC_EPB 8
__global__ __launch_bounds__(256) void k_scatter_w(const int* __restrict__ src,
                                                   const int* __restrict__ dst,
                                                   int* __restrict__ rowcur,
                                                   int* __restrict__ esrc,
                                                   int ne, int wsz) {
    const int w = blockIdx.x & 7;
    const int chunk = blockIdx.x >> 3;
    const int wlo = w * wsz;
    const int whi = wlo + wsz;
    int base = chunk * (256 * SC_EPB) + threadIdx.x;
    #pragma unroll
    for (int j = 0; j < SC_EPB; ++j) {
        int i = base + j * 256;
        if (i < ne) {
            int d = dst[i];
            if (d >= wlo && d < whi) {
                int pos = atomicAdd(&rowcur[d], 1);
                esrc[pos] = src[i];
            }
        }
    }
}

// ---------------- W prep: Wt[c][k] = bf16(W[k][c]) ----------------
__global__ __launch_bounds__(256) void k_wprep(const float* __restrict__ W,
                                               ushort16* __restrict__ Wt,
                                               int rows, int cols) {
    int i = blockIdx.x * 256 + threadIdx.x;
    if (i >= rows * cols) return;
    int c = i / rows, k = i % rows;
    Wt[i] = f2bf(W[k * cols + c]);
}

// ---------------- MFMA GEMM: C(bf16) = act(A) @ W ----------------
// A: fp32 (AF32) or packed bf16; optional fused BN+ReLU during staging.
template<int COLS, bool BN, bool AF32>
__global__ __launch_bounds__(256) void k_gemm_mfma(const void* __restrict__ Av,
                                                   const ushort16* __restrict__ Wt,
                                                   const float* __restrict__ ss,
                                                   ushort16* __restrict__ C, int nrows) {
    constexpr int K = 128;
    constexpr int LDK = K + 8;  // pad 16B: lane-row stride 272B -> 2-way banks (free)
    __shared__ ushort16 As[64 * LDK];
    __shared__ ushort16 Bs[COLS * LDK];
    const int tid = threadIdx.x;
    const int row0 = blockIdx.x * 64;

    {
        const uint4* wg = (const uint4*)Wt;
        for (int i = tid; i < COLS * (K / 8); i += 256) {
            int r = i >> 4, c8 = i & 15;
            *(uint4*)&Bs[r * LDK + c8 * 8] = wg[i];
        }
    }
    if constexpr (AF32) {
        const float* A = (const float*)Av;
        for (int i = tid; i < 64 * (K / 4); i += 256) {
            int r = i >> 5, c4 = i & 31;
            float4 a;
            if (row0 + r < nrows) a = *(const float4*)&A[(size_t)(row0 + r) * K + c4 * 4];
            else a = make_float4(0.f, 0.f, 0.f, 0.f);
            if (BN) {
                float4 sc = *(const float4*)&ss[c4 * 4];
                float4 sh = *(const float4*)&ss[128 + c4 * 4];
                a.x = fmaxf(fmaf(a.x, sc.x, sh.x), 0.f);
                a.y = fmaxf(fmaf(a.y, sc.y, sh.y), 0.f);
                a.z = fmaxf(fmaf(a.z, sc.z, sh.z), 0.f);
                a.w = fmaxf(fmaf(a.w, sc.w, sh.w), 0.f);
            }
            ushort4 o;
            o.x = f2bf(a.x); o.y = f2bf(a.y); o.z = f2bf(a.z); o.w = f2bf(a.w);
            *(ushort4*)&As[r * LDK + c4 * 4] = o;
        }
    } else {
        const uint4* Ag = (const uint4*)Av;
        for (int i = tid; i < 64 * (K / 8); i += 256) {
            int r = i >> 4, c8 = i & 15;
            uint4 u;
            if (row0 + r < nrows) u = Ag[(size_t)(row0 + r) * 16 + c8];
            else u = make_uint4(0, 0, 0, 0);
            if (BN) {
                uint32 wv[4] = {u.x, u.y, u.z, u.w};
                #pragma unroll
                for (int t = 0; t < 4; ++t) {
                    int f = c8 * 8 + t * 2;
                    float lo = fmaxf(fmaf(bf2f(wv[t] & 0xffffu), ss[f],     ss[128 + f]),     0.f);
                    float hi = fmaxf(fmaf(bf2f(wv[t] >> 16),     ss[f + 1], ss[128 + f + 1]), 0.f);
                    wv[t] = pack2(lo, hi);
                }
                u.x = wv[0]; u.y = wv[1]; u.z = wv[2]; u.w = wv[3];
            }
            *(uint4*)&As[r * LDK + c8 * 8] = u;
        }
    }
    __syncthreads();

    const int w = tid >> 6;
    const int l = tid & 63;
    const int lr = l & 15;
    const int lg = l >> 4;
    constexpr int CT = COLS / 16;

    float4v acc[CT] = {};
    short8v afrag[4];
    #pragma unroll
    for (int kk = 0; kk < 4; ++kk)
        afrag[kk] = *(const short8v*)&As[(w * 16 + lr) * LDK + kk * 32 + lg * 8];
    #pragma unroll
    for (int kk = 0; kk < 4; ++kk) {
        #pragma unroll
        for (int ct = 0; ct < CT; ++ct) {
            short8v b = *(const short8v*)&Bs[(ct * 16 + lr) * LDK + kk * 32 + lg * 8];
            acc[ct] = __builtin_amdgcn_mfma_f32_16x16x32_bf16(afrag[kk], b, acc[ct], 0, 0, 0);
        }
    }
    #pragma unroll
    for (int ct = 0; ct < CT; ++ct) {
        #pragma unroll
        for (int r = 0; r < 4; ++r) {
            int gr = row0 + w * 16 + lg * 4 + r;
            if (gr < nrows) C[(size_t)gr * COLS + ct * 16 + lr] = f2bf(acc[ct][r]);
        }
    }
}

// ---------------- CSR aggregation (bf16 gather, fp32 accum, bf16 out) ----------------
template<int COLS>
__global__ __launch_bounds__(256) void k_agg_csr(const ushort16* __restrict__ h,
                                                 const int* __restrict__ rowstart,
                                                 const int* __restrict__ cnt,
                                                 const int* __restrict__ esrc,
                                                 const float* __restrict__ dinv,
                                                 uint32* __restrict__ out, int n) {
    constexpr int TPN = COLS / 2;
    const uint32* __restrict__ hu = (const uint32*)h;
    int gt = blockIdx.x * 256 + threadIdx.x;
    int node = gt / TPN;
    if (node >= n) return;
    int lane = gt % TPN;

    float di = dinv[node];
    uint32 p = hu[(size_t)node * TPN + lane];
    float ax = bf2f(p & 0xffffu) * di * di;
    float ay = bf2f(p >> 16) * di * di;

    const int beg = rowstart[node];
    const int end = beg + cnt[node];
    int e = beg;
    for (; e + 4 <= end; e += 4) {
        int s0 = esrc[e], s1 = esrc[e + 1], s2 = esrc[e + 2], s3 = esrc[e + 3];
        float w0 = dinv[s0] * di, w1 = dinv[s1] * di;
        float w2 = dinv[s2] * di, w3 = dinv[s3] * di;
        uint32 p0 = hu[(size_t)s0 * TPN + lane];
        uint32 p1 = hu[(size_t)s1 * TPN + lane];
        uint32 p2 = hu[(size_t)s2 * TPN + lane];
        uint32 p3 = hu[(size_t)s3 * TPN + lane];
        ax = fmaf(bf2f(p0 & 0xffffu), w0, ax); ay = fmaf(bf2f(p0 >> 16), w0, ay);
        ax = fmaf(bf2f(p1 & 0xffffu), w1, ax); ay = fmaf(bf2f(p1 >> 16), w1, ay);
        ax = fmaf(bf2f(p2 & 0xffffu), w2, ax); ay = fmaf(bf2f(p2 >> 16), w2, ay);
        ax = fmaf(bf2f(p3 & 0xffffu), w3, ax); ay = fmaf(bf2f(p3 >> 16), w3, ay);
    }
    for (; e < end; ++e) {
        int s0 = esrc[e];
        float w0 = dinv[s0] * di;
        uint32 p0 = hu[(size_t)s0 * TPN + lane];
        ax = fmaf(bf2f(p0 & 0xffffu), w0, ax);
        ay = fmaf(bf2f(p0 >> 16), w0, ay);
    }
    out[(size_t)node * TPN + lane] = pack2(ax, ay);
}

// ---------------- BatchNorm stats: 2-stage reduction over packed-bf16 x ----------------
__global__ __launch_bounds__(256) void k_bn_stats1(const uint32* __restrict__ x,
                                                   float* __restrict__ partials, int n) {
    const int cp = threadIdx.x & 63;   // uint32 column -> feats 2cp, 2cp+1
    const int rl = threadIdx.x >> 6;   // 0..3 row-lane
    float s0 = 0.f, s1 = 0.f, q0 = 0.f, q1 = 0.f;
    for (int r = blockIdx.x * 4 + rl; r < n; r += BN_BLOCKS * 4) {
        uint32 u = x[(size_t)r * 64 + cp];
        float lo = bf2f(u & 0xffffu), hi = bf2f(u >> 16);
        s0 += lo; s1 += hi;
        q0 = fmaf(lo, lo, q0); q1 = fmaf(hi, hi, q1);
    }
    __shared__ float shs[4 * 128];
    __shared__ float shq[4 * 128];
    shs[rl * 128 + 2 * cp] = s0; shs[rl * 128 + 2 * cp + 1] = s1;
    shq[rl * 128 + 2 * cp] = q0; shq[rl * 128 + 2 * cp + 1] = q1;
    __syncthreads();
    int f = threadIdx.x;
    if (f < 128) {
        float s = shs[f] + shs[128 + f] + shs[256 + f] + shs[384 + f];
        float q = shq[f] + shq[128 + f] + shq[256 + f] + shq[384 + f];
        partials[(size_t)blockIdx.x * 256 + f] = s;
        partials[(size_t)blockIdx.x * 256 + 128 + f] = q;
    }
}

__global__ __launch_bounds__(256) void k_bn_stats2(const float* __restrict__ partials,
                                                   float* __restrict__ stats) {
    int j = threadIdx.x;
    float acc = 0.f;
    int r0 = blockIdx.x * (BN_BLOCKS / 8);
    for (int r = 0; r < BN_BLOCKS / 8; ++r)
        acc += partials[(size_t)(r0 + r) * 256 + j];
    atomicAdd(&stats[j], acc);
}

__global__ __launch_bounds__(128) void k_bn_final(const float* __restrict__ stats,
                                                  const float* __restrict__ gamma,
                                                  const float* __restrict__ beta,
                                                  float* __restrict__ ss, int n) {
    int f = threadIdx.x;
    float inv_n = 1.0f / (float)n;
    float mean = stats[f] * inv_n;
    float var = stats[128 + f] * inv_n - mean * mean;
    float scale = gamma[f] * rsqrtf(var + EPS_BN);
    ss[f] = scale;
    ss[128 + f] = beta[f] - mean * scale;
}

// ---------------- pool: sorted-batch run-length private accumulation (bf16 in) ----------------
#define POOL_SLICE 128
__global__ __launch_bounds__(256) void k_pool2(const uint32* __restrict__ h3,
                                               const int* __restrict__ batch,
                                               float* __restrict__ sums,
                                               float* __restrict__ cnt, int n) {
    const int fp = threadIdx.x & 15;       // uint32 pair -> feats 2fp, 2fp+1
    const int sub = threadIdx.x >> 4;      // 16 slices per block
    int node0 = blockIdx.x * (16 * POOL_SLICE) + sub * POOL_SLICE;
    if (node0 >= n) return;
    int node1 = min(node0 + POOL_SLICE, n);

    int cur_g = batch[node0];
    float a0 = 0.f, a1 = 0.f, c = 0.f;
    for (int i = node0; i < node1; ++i) {
        int g = batch[i];
        if (g != cur_g) {
            atomicAdd(&sums[cur_g * 32 + 2 * fp], a0);
            atomicAdd(&sums[cur_g * 32 + 2 * fp + 1], a1);
            if (fp == 0) atomicAdd(&cnt[cur_g], c);
            a0 = 0.f; a1 = 0.f; c = 0.f; cur_g = g;
        }
        uint32 u = h3[(size_t)i * 16 + fp];
        a0 += bf2f(u & 0xffffu);
        a1 += bf2f(u >> 16);
        c += 1.f;
    }
    atomicAdd(&sums[cur_g * 32 + 2 * fp], a0);
    atomicAdd(&sums[cur_g * 32 + 2 * fp + 1], a1);
    if (fp == 0) atomicAdd(&cnt[cur_g], c);
}

__global__ __launch_bounds__(256) void k_final(const float* __restrict__ sums,
                                               const float* __restrict__ cnt,
                                               const float* __restrict__ b3,
                                               float* __restrict__ out) {
    int i = blockIdx.x * 256 + threadIdx.x;
    if (i >= NGRAPH * 32) return;
    int g = i >> 5;
    int f = i & 31;
    float c = fmaxf(cnt[g], 1.0f);
    float v = sums[i] / c + b3[f];
    out[i] = 1.0f / (1.0f + expf(-v));
}

// ---------------- launch ----------------
extern "C" void kernel_launch(void* const* d_in, const int* in_sizes, int n_in,
                              void* d_out, int out_size, void* d_ws, size_t ws_size,
                              hipStream_t stream) {
    const float* x      = (const float*)d_in[0];
    const int*   eidx   = (const int*)d_in[1];
    const int*   batch  = (const int*)d_in[2];
    const float* W1     = (const float*)d_in[3];
    const float* W2     = (const float*)d_in[5];
    const float* W3     = (const float*)d_in[7];
    const float* b3     = (const float*)d_in[8];
    const float* gamma1 = (const float*)d_in[9];
    const float* beta1  = (const float*)d_in[10];
    const float* gamma2 = (const float*)d_in[11];
    const float* beta2  = (const float*)d_in[12];

    const int N = in_sizes[0] / 128;
    const int E = in_sizes[1] / 2;
    const int* src = eidx;
    const int* dst = eidx + E;

    size_t off = 0;
    auto carve = [&](size_t bytes) {
        char* p = (char*)d_ws + off;
        off += (bytes + 511) & ~(size_t)511;
        return p;
    };
    const size_t NB = (size_t)N * 128 * sizeof(float);
    ushort16* bufA  = (ushort16*)carve(NB / 2);     // bf16 h (gather source)
    uint32* bufB    = (uint32*)carve(NB / 2);       // bf16 agg output (packed)
    int*   cnt      = (int*)carve((size_t)N * 4);
    int*   rowstart = (int*)carve((size_t)N * 4);
    int*   rowcur   = (int*)carve((size_t)N * 4);
    float* dinv     = (float*)carve((size_t)N * 4);
    int*   esrc     = (int*)carve((size_t)E * 4);
    ushort16* wt1   = (ushort16*)carve(128 * 128 * 2);
    ushort16* wt2   = (ushort16*)carve(128 * 128 * 2);
    ushort16* wt3   = (ushort16*)carve(32 * 128 * 2);
    float* stats    = (float*)carve(256 * 4);
    float* ss1      = (float*)carve(256 * 4);
    float* ss2      = (float*)carve(256 * 4);
    float* partials = (float*)carve((size_t)BN_BLOCKS * 256 * 4);
    int*   blocksum = (int*)carve(1024 * 4);
    float* psum     = (float*)carve(NGRAPH * 32 * 4);
    float* pcnt     = (float*)carve(NGRAPH * 4);
    (void)ws_size; (void)n_in; (void)out_size;

    const int nblkN   = (N + 255) / 256;
    const int nblkE   = (E + 255) / 256;
    const int nbScan  = (N + 1023) / 1024;
    const int nbGemm  = (N + 63) / 64;
    const int nblkAgg128 = ((size_t)N * 64 + 255) / 256;
    const int nblkAgg32  = ((size_t)N * 16 + 255) / 256;
    const int nblkPool   = (N + 16 * POOL_SLICE - 1) / (16 * POOL_SLICE);
    const int wsz        = (N + 7) / 8;
    const int nbScat     = ((E + 256 * SC_EPB - 1) / (256 * SC_EPB)) * 8;

    // --- W prep (bf16, transposed) ---
    k_wprep<<<(128 * 128 + 255) / 256, 256, 0, stream>>>(W1, wt1, 128, 128);
    k_wprep<<<(128 * 128 + 255) / 256, 256, 0, stream>>>(W2, wt2, 128, 128);
    k_wprep<<<(32 * 128 + 255) / 256, 256, 0, stream>>>(W3, wt3, 128, 32);

    // --- CSR build ---
    hipMemsetAsync(cnt, 0, (size_t)N * 4, stream);
    k_cnt<<<nblkE, 256, 0, stream>>>(dst, cnt, E);
    k_scan1<<<nbScan, 1024, 0, stream>>>(cnt, rowstart, blocksum, dinv, N);
    k_scan2<<<1, 1024, 0, stream>>>(blocksum, nbScan);
    k_scan3<<<nblkN, 256, 0, stream>>>(rowstart, rowcur, blocksum, N);
    k_scatter_w<<<nbScat, 256, 0, stream>>>(src, dst, rowcur, esrc, E, wsz);

    // --- layer 1 (b1 cancels under BN) ---
    k_gemm_mfma<128, false, true><<<nbGemm, 256, 0, stream>>>(x, wt1, nullptr, bufA, N);
    k_agg_csr<128><<<nblkAgg128, 256, 0, stream>>>(bufA, rowstart, cnt, esrc, dinv, bufB, N);
    k_bn_stats1<<<BN_BLOCKS, 256, 0, stream>>>(bufB, partials, N);
    hipMemsetAsync(stats, 0, 256 * 4, stream);
    k_bn_stats2<<<8, 256, 0, stream>>>(partials, stats);
    k_bn_final<<<1, 128, 0, stream>>>(stats, gamma1, beta1, ss1, N);

    // --- layer 2 (BN1+ReLU fused into A-staging, bf16 A) ---
    k_gemm_mfma<128, true, false><<<nbGemm, 256, 0, stream>>>(bufB, wt2, ss1, bufA, N);
    k_agg_csr<128><<<nblkAgg128, 256, 0, stream>>>(bufA, rowstart, cnt, esrc, dinv, bufB, N);
    k_bn_stats1<<<BN_BLOCKS, 256, 0, stream>>>(bufB, partials, N);
    hipMemsetAsync(stats, 0, 256 * 4, stream);
    k_bn_stats2<<<8, 256, 0, stream>>>(partials, stats);
    k_bn_final<<<1, 128, 0, stream>>>(stats, gamma2, beta2, ss2, N);

    // --- layer 3 (128 -> 32, BN2+ReLU fused, bf16 A) ---
    k_gemm_mfma<32, true, false><<<nbGemm, 256, 0, stream>>>(bufB, wt3, ss2, bufA, N);
    k_agg_csr<32><<<nblkAgg32, 256, 0, stream>>>(bufA, rowstart, cnt, esrc, dinv, bufB, N);

    // --- pool + sigmoid (b3 added post-pool) ---
    hipMemsetAsync(psum, 0, NGRAPH * 32 * 4, stream);
    hipMemsetAsync(pcnt, 0, NGRAPH * 4, stream);
    k_pool2<<<nblkPool, 256, 0, stream>>>(bufB, batch, psum, pcnt, N);
    k_final<<<(NGRAPH * 32 + 255) / 256, 256, 0, stream>>>(psum, pcnt, b3, (float*)d_out);
}